// Round 16
// baseline (3775.436 us; speedup 1.0000x reference)
//
#include <hip/hip_runtime.h>
#include <hip/hip_bf16.h>

// ---- problem constants ----
constexpr int BATCH = 4;
constexpr int NTOK  = 6085;            // 1 cls + 6084 (wrap-padded to 78^2)
constexpr int BN_TOK = BATCH * NTOK;   // 24340
constexpr int NPD   = 6144;            // 6085 front-padded to multiple of 256
constexpr int RPAD  = BATCH * NPD;     // 24576
constexpr int DMODEL = 512;
constexpr int NH = 8, DH = 64;
constexpr int NBH = BATCH * NH;        // 32
constexpr int LGRP = NPD / 256;        // 24 tokens per landmark
constexpr int PAD_FRONT = 59;
constexpr int CONVK = 33;
constexpr int NCH = 8;                 // attn3 kv chunks
constexpr int LISTCAP = 24576;         // per-expert token list capacity

typedef __attribute__((ext_vector_type(8))) short short8v;
typedef __attribute__((ext_vector_type(4))) float f32x4;

__device__ __forceinline__ unsigned short f2bf(float f) {
  unsigned u = __float_as_uint(f);
  u += 0x7FFF + ((u >> 16) & 1);
  return (unsigned short)(u >> 16);
}
__device__ __forceinline__ float bf2f(unsigned short h) {
  return __uint_as_float((unsigned)h << 16);
}

// ============================ kernels ============================

__global__ void k_build_h(const float* __restrict__ feat, const float* __restrict__ cls,
                          float* __restrict__ H) {
  size_t total = (size_t)BN_TOK * DMODEL;
  for (size_t idx = (size_t)blockIdx.x * blockDim.x + threadIdx.x; idx < total;
       idx += (size_t)gridDim.x * blockDim.x) {
    int d = (int)(idx & 511);
    size_t tok = idx >> 9;
    int b = (int)(tok / NTOK), n = (int)(tok % NTOK);
    float v;
    if (n == 0) v = cls[d];
    else {
      int i = n - 1; if (i >= 6000) i -= 6000;
      v = feat[((size_t)b * 6000 + i) * DMODEL + d];
    }
    H[idx] = v;
  }
}

__global__ void k_diag_fill(float* __restrict__ out, size_t n, float val) {
  for (size_t i = (size_t)blockIdx.x * blockDim.x + threadIdx.x; i < n;
       i += (size_t)gridDim.x * blockDim.x)
    out[i] = val;
}

// weight convert: W fp32 [512][ldb] (use N cols) -> hi/lo bf16 [N][512] (transposed)
__global__ __launch_bounds__(256) void k_wconv(const float* __restrict__ W, int ldb,
    unsigned short* __restrict__ hi, unsigned short* __restrict__ lo) {
  __shared__ unsigned short Th[64][80], Tl[64][80];
  int bk = blockIdx.y * 64, bn = blockIdx.x * 64;
  int t = threadIdx.x;
  int kr = t >> 2, cq = (t & 3) * 16;
  const float* src = W + (size_t)(bk + kr) * ldb + bn + cq;
  #pragma unroll
  for (int q = 0; q < 4; ++q) {
    float4 v = *(const float4*)(src + q * 4);
    float vs[4] = {v.x, v.y, v.z, v.w};
    #pragma unroll
    for (int e = 0; e < 4; ++e) {
      int n = cq + q * 4 + e;
      unsigned short h = f2bf(vs[e]);
      Th[n][kr] = h;
      Tl[n][kr] = f2bf(vs[e] - bf2f(h));
    }
  }
  __syncthreads();
  int nr = t >> 2, kq = (t & 3) * 16;
  size_t o = (size_t)(bn + nr) * 512 + bk + kq;
  *(short8v*)&hi[o]     = *(const short8v*)&Th[nr][kq];
  *(short8v*)&hi[o + 8] = *(const short8v*)&Th[nr][kq + 8];
  *(short8v*)&lo[o]     = *(const short8v*)&Tl[nr][kq];
  *(short8v*)&lo[o + 8] = *(const short8v*)&Tl[nr][kq + 8];
}

// per-expert token list build: wave ballot compaction, grouped atomic base.
__global__ void k_lists(const float* __restrict__ WT, int* __restrict__ cnt,
                        int* __restrict__ lists, int E) {
  int lane = threadIdx.x;
  int tok = blockIdx.x * 64 + lane;
  for (int e = 0; e < E; ++e) {
    bool sel = (tok < BN_TOK) && (WT[(size_t)tok * 4 + e] != 0.f);
    unsigned long long mask = __ballot(sel);
    int rank = __popcll(mask & ((1ull << lane) - 1ull));
    int n = __popcll(mask);
    int base = 0;
    if (lane == 0 && n > 0) base = atomicAdd(&cnt[e], n);
    base = __shfl(base, 0);
    if (sel) lists[(size_t)e * LISTCAP + base + rank] = tok;
  }
}

// ---- bf16x3 MFMA GEMM: C = alpha*(A@B)+bias. A fp32 [M][lda] (in-kernel split),
// Bt hi/lo bf16 [N][512]. In-loop loads + XCD-chunked block swizzle.
// Optional row gather/scatter: rowidx/cnt (per-expert MoE token lists).
// omode 0: fp32 C; 2: resid-accum crop pad; 3: head-split fp32; 6: head-split hi/lo
__global__ __launch_bounds__(256) void k_gemm_mfma(const float* __restrict__ A,
    const unsigned short* __restrict__ BtH, const unsigned short* __restrict__ BtL,
    const float* __restrict__ bias, float* __restrict__ C,
    int M, int lda, int ldc, float alpha, int omode, unsigned short* __restrict__ Clo,
    const int* __restrict__ rowidx, const int* __restrict__ cnt)
{
  __shared__ unsigned short AsH[128][40], AsL[128][40];
  __shared__ unsigned short BsH[128][40], BsL[128][40];
  // XCD-chunked bijective block swizzle (m204 form)
  int nwg = gridDim.x * gridDim.y;
  int wid = blockIdx.y * gridDim.x + blockIdx.x;
  int qq = nwg >> 3, rr = nwg & 7;
  int xcd = wid & 7, pos = wid >> 3;
  int Lid = (xcd < rr ? xcd * (qq + 1) : rr * (qq + 1) + (xcd - rr) * qq) + pos;
  int bn = (Lid % gridDim.x) * 128;
  int bm = (Lid / gridDim.x) * 128;
  int Mv = M;
  if (cnt) { Mv = *cnt; if (Mv > M) Mv = M; }
  if (bm >= Mv) return;
  int tid = threadIdx.x;
  int wave = tid >> 6, lane = tid & 63;
  int mo = (wave >> 1) * 64, no = (wave & 1) * 64;
  int r16 = lane & 15, g = lane >> 4;
  f32x4 acc[4][4] = {};
  int srow = tid >> 1, shalf = (tid & 1) * 16;
  int lrow = bm + srow;
  bool avalid = lrow < Mv;
  int arow = lrow;
  if (rowidx && avalid) arow = rowidx[lrow];
  if (!avalid) arow = 0;
  const float* aptr = A + (size_t)arow * lda + shalf;
  const unsigned short* bhptr = BtH + (size_t)(bn + srow) * 512 + shalf;
  const unsigned short* blptr = BtL + (size_t)(bn + srow) * 512 + shalf;
  for (int k0 = 0; k0 < 512; k0 += 32) {
    unsigned short h8[16], l8[16];
    #pragma unroll
    for (int q = 0; q < 4; ++q) {
      float4 v = avalid ? *(const float4*)(aptr + k0 + q * 4) : make_float4(0.f, 0.f, 0.f, 0.f);
      float vs[4] = {v.x, v.y, v.z, v.w};
      #pragma unroll
      for (int e = 0; e < 4; ++e) {
        unsigned short hh = f2bf(vs[e]);
        h8[q * 4 + e] = hh;
        l8[q * 4 + e] = f2bf(vs[e] - bf2f(hh));
      }
    }
    *(short8v*)&AsH[srow][shalf]     = *(short8v*)&h8[0];
    *(short8v*)&AsH[srow][shalf + 8] = *(short8v*)&h8[8];
    *(short8v*)&AsL[srow][shalf]     = *(short8v*)&l8[0];
    *(short8v*)&AsL[srow][shalf + 8] = *(short8v*)&l8[8];
    *(short8v*)&BsH[srow][shalf]     = *(const short8v*)(bhptr + k0);
    *(short8v*)&BsH[srow][shalf + 8] = *(const short8v*)(bhptr + k0 + 8);
    *(short8v*)&BsL[srow][shalf]     = *(const short8v*)(blptr + k0);
    *(short8v*)&BsL[srow][shalf + 8] = *(const short8v*)(blptr + k0 + 8);
    __syncthreads();
    short8v ah[4], al[4], bh[4], bl[4];
    #pragma unroll
    for (int mt = 0; mt < 4; ++mt) {
      ah[mt] = *(const short8v*)&AsH[mo + mt * 16 + r16][g * 8];
      al[mt] = *(const short8v*)&AsL[mo + mt * 16 + r16][g * 8];
    }
    #pragma unroll
    for (int nt = 0; nt < 4; ++nt) {
      bh[nt] = *(const short8v*)&BsH[no + nt * 16 + r16][g * 8];
      bl[nt] = *(const short8v*)&BsL[no + nt * 16 + r16][g * 8];
    }
    #pragma unroll
    for (int mt = 0; mt < 4; ++mt)
      #pragma unroll
      for (int nt = 0; nt < 4; ++nt) {
        acc[mt][nt] = __builtin_amdgcn_mfma_f32_16x16x32_bf16(ah[mt], bh[nt], acc[mt][nt], 0, 0, 0);
        acc[mt][nt] = __builtin_amdgcn_mfma_f32_16x16x32_bf16(ah[mt], bl[nt], acc[mt][nt], 0, 0, 0);
        acc[mt][nt] = __builtin_amdgcn_mfma_f32_16x16x32_bf16(al[mt], bh[nt], acc[mt][nt], 0, 0, 0);
      }
    __syncthreads();
  }
  #pragma unroll
  for (int mt = 0; mt < 4; ++mt)
    #pragma unroll
    for (int nt = 0; nt < 4; ++nt)
      #pragma unroll
      for (int j = 0; j < 4; ++j) {
        int lr = bm + mo + mt * 16 + g * 4 + j;
        int gc = bn + no + nt * 16 + r16;
        if (lr >= Mv) continue;
        int gr = rowidx ? rowidx[lr] : lr;
        float v = alpha * acc[mt][nt][j] + (bias ? bias[gc] : 0.f);
        if (omode == 0) {
          C[(size_t)gr * ldc + gc] = v;
        } else if (omode == 2) {
          int bb = gr / NPD, ii = gr % NPD;
          if (ii >= PAD_FRONT)
            C[((size_t)bb * NTOK + ii - PAD_FRONT) * 512 + gc] += v;
        } else if (omode == 3) {
          int bb = gr / NPD, ii = gr % NPD;
          int hh = gc >> 6, dd = gc & 63;
          C[(((size_t)bb * NH + hh) * NPD + ii) * 64 + dd] = v;
        } else {  // omode 6: packed head-split hi/lo
          int bb = gr / NPD, ii = gr % NPD;
          int hh = gc >> 6, dd = gc & 63;
          size_t idx = (((size_t)bb * NH + hh) * NPD + ii) * 64 + dd;
          unsigned short hi = f2bf(v);
          ((unsigned short*)C)[idx] = hi;
          Clo[idx] = f2bf(v - bf2f(hi));
        }
      }
}

// ---- bf16 MFMA GEMM, both fp32, batched 256x256x256 (pinv). nprod=1 or 3 ----
__global__ __launch_bounds__(256) void k_gemm_mfma2(const float* __restrict__ A,
    const float* __restrict__ Bt, float* __restrict__ C,
    float alpha, int omode, float cdiag, int premap, int nprod)
{
  __shared__ unsigned short AsH[128][40], AsL[128][40];
  __shared__ unsigned short BsH[128][40], BsL[128][40];
  size_t zo = (size_t)blockIdx.z * 65536;
  int bm = blockIdx.y * 128, bn = blockIdx.x * 128;
  int tid = threadIdx.x;
  int wave = tid >> 6, lane = tid & 63;
  int mo = (wave >> 1) * 64, no = (wave & 1) * 64;
  int r16 = lane & 15, g = lane >> 4;
  f32x4 acc[4][4] = {};
  int srow = tid >> 1, shalf = (tid & 1) * 16;
  int grow = bm + srow;
  int gn = bn + srow;
  for (int k0 = 0; k0 < 256; k0 += 32) {
    unsigned short h8[16], l8[16];
    #pragma unroll
    for (int q = 0; q < 4; ++q) {
      float4 v = *(const float4*)&A[zo + (size_t)grow * 256 + k0 + shalf + q * 4];
      float vs[4] = {v.x, v.y, v.z, v.w};
      #pragma unroll
      for (int e = 0; e < 4; ++e) {
        float a = vs[e];
        if (premap) a = ((grow == (k0 + shalf + q * 4 + e)) ? 7.f : 0.f) - a;
        unsigned short hh = f2bf(a);
        h8[q * 4 + e] = hh;
        l8[q * 4 + e] = (nprod == 3) ? f2bf(a - bf2f(hh)) : (unsigned short)0;
      }
    }
    *(short8v*)&AsH[srow][shalf]     = *(short8v*)&h8[0];
    *(short8v*)&AsH[srow][shalf + 8] = *(short8v*)&h8[8];
    *(short8v*)&AsL[srow][shalf]     = *(short8v*)&l8[0];
    *(short8v*)&AsL[srow][shalf + 8] = *(short8v*)&l8[8];
    #pragma unroll
    for (int q = 0; q < 4; ++q) {
      float4 v = *(const float4*)&Bt[zo + (size_t)gn * 256 + k0 + shalf + q * 4];
      float vs[4] = {v.x, v.y, v.z, v.w};
      #pragma unroll
      for (int e = 0; e < 4; ++e) {
        unsigned short hh = f2bf(vs[e]);
        h8[q * 4 + e] = hh;
        l8[q * 4 + e] = (nprod == 3) ? f2bf(vs[e] - bf2f(hh)) : (unsigned short)0;
      }
    }
    *(short8v*)&BsH[srow][shalf]     = *(short8v*)&h8[0];
    *(short8v*)&BsH[srow][shalf + 8] = *(short8v*)&h8[8];
    *(short8v*)&BsL[srow][shalf]     = *(short8v*)&l8[0];
    *(short8v*)&BsL[srow][shalf + 8] = *(short8v*)&l8[8];
    __syncthreads();
    short8v ah[4], al[4], bh[4], bl[4];
    #pragma unroll
    for (int mt = 0; mt < 4; ++mt) {
      ah[mt] = *(const short8v*)&AsH[mo + mt * 16 + r16][g * 8];
      al[mt] = *(const short8v*)&AsL[mo + mt * 16 + r16][g * 8];
    }
    #pragma unroll
    for (int nt = 0; nt < 4; ++nt) {
      bh[nt] = *(const short8v*)&BsH[no + nt * 16 + r16][g * 8];
      bl[nt] = *(const short8v*)&BsL[no + nt * 16 + r16][g * 8];
    }
    #pragma unroll
    for (int mt = 0; mt < 4; ++mt)
      #pragma unroll
      for (int nt = 0; nt < 4; ++nt) {
        acc[mt][nt] = __builtin_amdgcn_mfma_f32_16x16x32_bf16(ah[mt], bh[nt], acc[mt][nt], 0, 0, 0);
        if (nprod == 3) {
          acc[mt][nt] = __builtin_amdgcn_mfma_f32_16x16x32_bf16(ah[mt], bl[nt], acc[mt][nt], 0, 0, 0);
          acc[mt][nt] = __builtin_amdgcn_mfma_f32_16x16x32_bf16(al[mt], bh[nt], acc[mt][nt], 0, 0, 0);
        }
      }
    __syncthreads();
  }
  #pragma unroll
  for (int mt = 0; mt < 4; ++mt)
    #pragma unroll
    for (int nt = 0; nt < 4; ++nt)
      #pragma unroll
      for (int j = 0; j < 4; ++j) {
        int gr = bm + mo + mt * 16 + g * 4 + j;
        int gc = bn + no + nt * 16 + r16;
        float v;
        if (omode == 5) v = ((gr == gc) ? cdiag : 0.f) - acc[mt][nt][j];
        else            v = alpha * acc[mt][nt][j];
        C[zo + (size_t)gr * 256 + gc] = v;
      }
}

// batched [256][256] fp32 transpose. grid (4,4,NBH)
__global__ __launch_bounds__(256) void k_tpose(const float* __restrict__ in,
                                               float* __restrict__ out) {
  __shared__ float Ts[64][65];
  int bx = blockIdx.x * 64, by = blockIdx.y * 64;
  size_t zo = (size_t)blockIdx.z * 65536;
  int t = threadIdx.x;
  int r = t >> 4, c4 = (t & 15) * 4;
  #pragma unroll
  for (int u = 0; u < 4; ++u) {
    float4 v = *(const float4*)&in[zo + (size_t)(by + r + u * 16) * 256 + bx + c4];
    Ts[r + u * 16][c4 + 0] = v.x; Ts[r + u * 16][c4 + 1] = v.y;
    Ts[r + u * 16][c4 + 2] = v.z; Ts[r + u * 16][c4 + 3] = v.w;
  }
  __syncthreads();
  #pragma unroll
  for (int u = 0; u < 4; ++u) {
    int rr = r + u * 16;
    float4 v = make_float4(Ts[c4][rr], Ts[c4 + 1][rr], Ts[c4 + 2][rr], Ts[c4 + 3][rr]);
    *(float4*)&out[zo + (size_t)(bx + rr) * 256 + by + c4] = v;
  }
}

__global__ void k_y0(const float* __restrict__ A2, float* __restrict__ Y,
                     const unsigned int* __restrict__ sc) {
  float scale = 1.f / (__uint_as_float(sc[0]) * __uint_as_float(sc[1]));
  size_t total = (size_t)NBH * 65536;
  for (size_t idx = (size_t)blockIdx.x * blockDim.x + threadIdx.x; idx < total;
       idx += (size_t)gridDim.x * blockDim.x)
    Y[idx] = A2[idx] * scale;
}

__global__ void k_zinit(const float* __restrict__ A2, float* __restrict__ Z,
                        const unsigned int* __restrict__ sc) {
  float scale = 1.f / (__uint_as_float(sc[0]) * __uint_as_float(sc[1]));
  size_t total = (size_t)NBH * 65536;
  for (size_t idx = (size_t)blockIdx.x * blockDim.x + threadIdx.x; idx < total;
       idx += (size_t)gridDim.x * blockDim.x) {
    size_t bh = idx >> 16; int r = (int)((idx >> 8) & 255); int cc = (int)(idx & 255);
    Z[idx] = A2[(bh << 16) + (size_t)cc * 256 + r] * scale;
  }
}

// --- 64x64-tile fp32 GEMM (small/batched shapes) ---
__global__ __launch_bounds__(256) void k_gemm(const float* __restrict__ A,
    const float* __restrict__ B,
    const float* __restrict__ bias, float* __restrict__ C,
    int M, int N, int K, int lda, int ldb, int ldc,
    long long sA, long long sB, long long sC, float alpha, int omode, float cdiag)
{
  __shared__ float As[16][65];
  __shared__ float Bs[16][65];
  int z = blockIdx.z;
  A += (size_t)z * (size_t)sA;
  B += (size_t)z * (size_t)sB;
  int bm = blockIdx.y * 64, bn = blockIdx.x * 64;
  int tid = threadIdx.x;
  int tr = tid >> 4, tc = tid & 15;
  int ar = tid >> 2, aq = tid & 3;
  int br = tid >> 4, bq = tid & 15;
  float acc[4][4] = {};
  for (int k0 = 0; k0 < K; k0 += 16) {
    {
      int gr = bm + ar;
      float4 v = make_float4(0.f, 0.f, 0.f, 0.f);
      if (gr < M) v = *(const float4*)&A[(size_t)gr * lda + k0 + aq * 4];
      As[aq * 4 + 0][ar] = v.x; As[aq * 4 + 1][ar] = v.y;
      As[aq * 4 + 2][ar] = v.z; As[aq * 4 + 3][ar] = v.w;
    }
    {
      float4 v = *(const float4*)&B[(size_t)(k0 + br) * ldb + bn + bq * 4];
      Bs[br][bq * 4 + 0] = v.x; Bs[br][bq * 4 + 1] = v.y;
      Bs[br][bq * 4 + 2] = v.z; Bs[br][bq * 4 + 3] = v.w;
    }
    __syncthreads();
    #pragma unroll
    for (int kk = 0; kk < 16; ++kk) {
      float a[4], bv[4];
      #pragma unroll
      for (int i = 0; i < 4; ++i) a[i] = As[kk][tr * 4 + i];
      #pragma unroll
      for (int j = 0; j < 4; ++j) bv[j] = Bs[kk][tc * 4 + j];
      #pragma unroll
      for (int i = 0; i < 4; ++i)
        #pragma unroll
        for (int j = 0; j < 4; ++j) acc[i][j] += a[i] * bv[j];
    }
    __syncthreads();
  }
  #pragma unroll
  for (int i = 0; i < 4; ++i) {
    int gr = bm + tr * 4 + i;
    if (gr >= M) continue;
    #pragma unroll
    for (int j = 0; j < 4; ++j) {
      int gc = bn + tc * 4 + j;
      float v;
      if (omode == 5) {
        v = ((gr == gc) ? cdiag : 0.f) - acc[i][j];
      } else {
        v = alpha * acc[i][j] + (bias ? bias[gc] : 0.f);
      }
      C[(size_t)z * (size_t)sC + (size_t)gr * ldc + gc] = v;
    }
  }
}

// gate scores + top-k softmax weights
__global__ void k_gate(const float* __restrict__ X, const float* __restrict__ gw,
                       const float* __restrict__ gb, float* __restrict__ WT, int E, int k) {
  int tok = blockIdx.x; int lane = threadIdx.x;
  const float* x = X + (size_t)tok * DMODEL;
  float s[4] = {0.f, 0.f, 0.f, 0.f};
  for (int d = lane; d < DMODEL; d += 64) {
    float xv = x[d];
    for (int e = 0; e < E; ++e) s[e] += xv * gw[(size_t)d * E + e];
  }
  #pragma unroll
  for (int off = 32; off; off >>= 1) {
    #pragma unroll
    for (int e = 0; e < 4; ++e) s[e] += __shfl_down(s[e], off);
  }
  if (lane == 0) {
    for (int e = 0; e < E; ++e) s[e] += gb[e];
    float w[4] = {0.f, 0.f, 0.f, 0.f};
    int i1 = 0;
    for (int e = 1; e < E; ++e) if (s[e] > s[i1]) i1 = e;
    if (k == 1) {
      w[i1] = 1.f;
    } else {
      int i2 = -1;
      for (int e = 0; e < E; ++e) { if (e == i1) continue; if (i2 < 0 || s[e] > s[i2]) i2 = e; }
      float e2 = expf(s[i2] - s[i1]);
      float zz = 1.f + e2;
      w[i1] = 1.f / zz; w[i2] = e2 / zz;
    }
    #pragma unroll
    for (int e = 0; e < 4; ++e) WT[(size_t)tok * 4 + e] = w[e];
  }
}

__device__ __forceinline__ void wave_ln_stats(const float* x, int lane, float& mu, float& rstd) {
  float s = 0.f, q = 0.f;
  #pragma unroll
  for (int j = 0; j < 8; ++j) { float v = x[lane + 64 * j]; s += v; q += v * v; }
  #pragma unroll
  for (int off = 32; off; off >>= 1) { s += __shfl_xor(s, off); q += __shfl_xor(q, off); }
  mu = s * (1.f / 512.f);
  float var = q * (1.f / 512.f) - mu * mu;
  rstd = rsqrtf(var + 1e-5f);
}

// gathered LN+ReLU: block i handles token lists[i] (skip if i >= cnt)
__global__ void k_ln_relu_g(float* __restrict__ T, const float* __restrict__ g,
                            const float* __restrict__ b,
                            const int* __restrict__ lists, const int* __restrict__ cnt) {
  int i = blockIdx.x;
  if (i >= *cnt) return;
  int row = lists[i];
  int lane = threadIdx.x;
  float* x = T + (size_t)row * 512;
  float mu, rstd; wave_ln_stats(x, lane, mu, rstd);
  #pragma unroll
  for (int j = 0; j < 8; ++j) {
    int d = lane + 64 * j;
    float v = (x[d] - mu) * rstd * g[d] + b[d];
    x[d] = fmaxf(v, 0.f);
  }
}

__global__ void k_ln_waccum(const float* __restrict__ T, float* __restrict__ H,
                            const float* __restrict__ g, const float* __restrict__ b,
                            const float* __restrict__ WT, int e) {
  int row = blockIdx.x;
  float w = WT[(size_t)row * 4 + e];
  if (w == 0.f) return;
  int lane = threadIdx.x;
  const float* x = T + (size_t)row * 512;
  float mu, rstd; wave_ln_stats(x, lane, mu, rstd);
  float* h = H + (size_t)row * 512;
  #pragma unroll
  for (int j = 0; j < 8; ++j) {
    int d = lane + 64 * j;
    h[d] += w * ((x[d] - mu) * rstd * g[d] + b[d]);
  }
}

__global__ void k_ln_pad(const float* __restrict__ H, float* __restrict__ XLn,
                         const float* __restrict__ g, const float* __restrict__ b) {
  int row = blockIdx.x; int lane = threadIdx.x;
  int bb = row / NPD, i = row % NPD;
  float* y = XLn + (size_t)row * 512;
  if (i < PAD_FRONT) {
    #pragma unroll
    for (int j = 0; j < 8; ++j) y[lane + 64 * j] = 0.f;
    return;
  }
  const float* x = H + ((size_t)bb * NTOK + (i - PAD_FRONT)) * 512;
  float mu, rstd; wave_ln_stats(x, lane, mu, rstd);
  #pragma unroll
  for (int j = 0; j < 8; ++j) {
    int d = lane + 64 * j;
    y[d] = (x[d] - mu) * rstd * g[d] + b[d];
  }
}

__global__ void k_xmean(const float* __restrict__ XLn, float* __restrict__ Xm) {
  int z = blockIdx.x;            // b*256 + jm
  int c = threadIdx.x;           // 512
  int b = z >> 8, jm = z & 255;
  const float* base = XLn + ((size_t)b * NPD + jm * LGRP) * 512 + c;
  float s = 0.f;
  #pragma unroll
  for (int t = 0; t < LGRP; ++t) s += base[(size_t)t * 512];
  Xm[(size_t)z * 512 + c] = s * (1.f / LGRP);
}

__global__ __launch_bounds__(256) void k_attn2(const float* __restrict__ QL,
                                               const float* __restrict__ KL,
                                               float* __restrict__ A2) {
  int z = blockIdx.x; int bh = z >> 8, j = z & 255;
  int b = bh >> 3, h = bh & 7;
  int t = threadIdx.x;
  __shared__ float q[64]; __shared__ float red[256];
  __shared__ float mshare, sshare;
  if (t < 64) q[t] = QL[((size_t)b * 256 + j) * 512 + h * 64 + t];
  __syncthreads();
  const float* kl = KL + ((size_t)b * 256 + t) * 512 + h * 64;
  float s = 0.f;
  #pragma unroll
  for (int d = 0; d < 64; ++d) s += q[d] * kl[d];
  red[t] = s; __syncthreads();
  for (int st = 128; st; st >>= 1) { if (t < st) red[t] = fmaxf(red[t], red[t + st]); __syncthreads(); }
  if (t == 0) mshare = red[0];
  __syncthreads();
  float e = expf(s - mshare);
  red[t] = e; __syncthreads();
  for (int st = 128; st; st >>= 1) { if (t < st) red[t] += red[t + st]; __syncthreads(); }
  if (t == 0) sshare = red[0];
  __syncthreads();
  A2[((size_t)bh * 256 + j) * 256 + t] = e / sshare;
}

__global__ __launch_bounds__(256) void k_pinv_scalars(const float* __restrict__ A2,
                                                      unsigned int* __restrict__ sc) {
  int bh = blockIdx.x; int t = threadIdx.x;
  const float* A = A2 + (size_t)bh * 65536;
  float rowsum = 0.f, colsum = 0.f;
  for (int jj = 0; jj < 256; ++jj) {
    rowsum += fabsf(A[(size_t)t * 256 + jj]);
    colsum += fabsf(A[(size_t)jj * 256 + t]);
  }
  __shared__ float sh[256];
  sh[t] = rowsum; __syncthreads();
  for (int s = 128; s; s >>= 1) { if (t < s) sh[t] = fmaxf(sh[t], sh[t + s]); __syncthreads(); }
  if (t == 0) atomicMax(&sc[0], __float_as_uint(sh[0]));
  __syncthreads();
  sh[t] = colsum; __syncthreads();
  for (int s = 128; s; s >>= 1) { if (t < s) sh[t] = fmaxf(sh[t], sh[t + s]); __syncthreads(); }
  if (t == 0) atomicMax(&sc[1], __float_as_uint(sh[0]));
}

// V [bh][NPD][64] hi/lo -> Vt [bh][64][NPD] hi/lo. grid (NPD/64, NBH)
__global__ __launch_bounds__(256) void k_vtpose(const unsigned short* __restrict__ VrH,
    const unsigned short* __restrict__ VrL,
    unsigned short* __restrict__ VtH, unsigned short* __restrict__ VtL) {
  __shared__ unsigned short TH[64][72], TL[64][72];
  int i0 = blockIdx.x * 64, bh = blockIdx.y;
  int t = threadIdx.x;
  const unsigned short* sH = VrH + ((size_t)bh * NPD + i0) * 64;
  const unsigned short* sL = VrL + ((size_t)bh * NPD + i0) * 64;
  #pragma unroll
  for (int u = 0; u < 2; ++u) {
    int idx = t + 256 * u;
    int r = idx >> 3, c8 = (idx & 7) * 8;
    *(short8v*)&TH[r][c8] = *(const short8v*)&sH[idx * 8];
    *(short8v*)&TL[r][c8] = *(const short8v*)&sL[idx * 8];
  }
  __syncthreads();
  #pragma unroll
  for (int u = 0; u < 2; ++u) {
    int idx = t + 256 * u;
    int d = idx >> 3, c8 = (idx & 7) * 8;
    unsigned short h8[8], l8[8];
    #pragma unroll
    for (int e = 0; e < 8; ++e) { h8[e] = TH[c8 + e][d]; l8[e] = TL[c8 + e][d]; }
    *(short8v*)&VtH[((size_t)bh * 64 + d) * NPD + i0 + c8] = *(short8v*)&h8[0];
    *(short8v*)&VtL[((size_t)bh * 64 + d) * NPD + i0 + c8] = *(short8v*)&l8[0];
  }
}

// KL [b][256][512] fp32 -> KLH/KLL [bh][256][64]. grid 2048 x 256
__global__ void k_cvt_kl(const float* __restrict__ KL, unsigned short* __restrict__ KH,
                         unsigned short* __restrict__ KLo) {
  int idx = blockIdx.x * 256 + threadIdx.x;
  int bh = idx >> 14, j = (idx >> 6) & 255, d = idx & 63;
  int b = bh >> 3, h = bh & 7;
  float v = KL[((size_t)b * 256 + j) * 512 + h * 64 + d];
  unsigned short hi = f2bf(v);
  KH[idx] = hi; KLo[idx] = f2bf(v - bf2f(hi));
}

// W2b [bh][256][64] fp32 -> W2t hi/lo [bh][64][256]. grid 2048 x 256
__global__ void k_cvt_w2t(const float* __restrict__ W2b, unsigned short* __restrict__ WH,
                          unsigned short* __restrict__ WL) {
  int idx = blockIdx.x * 256 + threadIdx.x;
  int bh = idx >> 14, d = (idx >> 8) & 63, j = idx & 255;
  float v = W2b[((size_t)bh * 256 + j) * 64 + d];
  unsigned short hi = f2bf(v);
  WH[idx] = hi; WL[idx] = f2bf(v - bf2f(hi));
}

// ---- MFMA flash attention, pre-split K/V; P hi-only PV ----
__global__ __launch_bounds__(256) void k_flash_pre(
    const float* __restrict__ Qp, long long Qsb, long long Qsh, int Qsr,
    const unsigned short* __restrict__ KHg, const unsigned short* __restrict__ KLg,
    long long Ksbh,
    const unsigned short* __restrict__ VtHg, const unsigned short* __restrict__ VtLg,
    long long Vsbh, int Vrow,
    float* __restrict__ Op, long long Osb, long long Osh, int Osr,
    float* __restrict__ Opart, float* __restrict__ ML,
    int tiles_per_chunk, int mode)
{
  int jt = blockIdx.x, bh = blockIdx.y, ch = blockIdx.z;
  int b = bh >> 3, h = bh & 7;
  const float* Qb = Qp + (size_t)b * Qsb + (size_t)h * Qsh;
  const unsigned short* KbH = KHg + (size_t)bh * Ksbh;
  const unsigned short* KbL = KLg + (size_t)bh * Ksbh;
  const unsigned short* VbH = VtHg + (size_t)bh * Vsbh;
  const unsigned short* VbL = VtLg + (size_t)bh * Vsbh;
  int tid = threadIdx.x;
  int wave = tid >> 6, lane = tid & 63;
  int r16 = lane & 15, g = lane >> 4;
  int q0 = jt * 64 + wave * 16;

  __shared__ unsigned short KsH[64][72], KsL[64][72];   // K; KsH reused as P after QK
  __shared__ unsigned short VtH[64][72], VtL[64][72];   // V transposed [d][key]

  short8v qh[2], ql[2];
  #pragma unroll
  for (int kk = 0; kk < 2; ++kk) {
    const float* qr = Qb + (size_t)(q0 + r16) * Qsr + kk * 32 + g * 8;
    float4 v0 = *(const float4*)qr;
    float4 v1 = *(const float4*)(qr + 4);
    float vs[8] = {v0.x, v0.y, v0.z, v0.w, v1.x, v1.y, v1.z, v1.w};
    unsigned short hh[8], llo[8];
    #pragma unroll
    for (int e = 0; e < 8; ++e) {
      hh[e] = f2bf(vs[e]); llo[e] = f2bf(vs[e] - bf2f(hh[e]));
    }
    qh[kk] = *(short8v*)&hh[0];
    ql[kk] = *(short8v*)&llo[0];
  }

  f32x4 O4[4] = {};
  float m[4], lsum[4];
  #pragma unroll
  for (int j = 0; j < 4; ++j) { m[j] = -1e30f; lsum[j] = 0.f; }

  int t0 = ch * tiles_per_chunk;
  for (int tt = t0; tt < t0 + tiles_per_chunk; ++tt) {
    int key0 = tt * 64;
    __syncthreads();
    {
      const unsigned short* ksrcH = KbH + (size_t)key0 * 64;
      const unsigned short* ksrcL = KbL + (size_t)key0 * 64;
      #pragma unroll
      for (int u = 0; u < 2; ++u) {
        int idx = tid + 256 * u;
        int r = idx >> 3, c8 = (idx & 7) * 8;
        *(short8v*)&KsH[r][c8] = *(const short8v*)&ksrcH[idx * 8];
        *(short8v*)&KsL[r][c8] = *(const short8v*)&ksrcL[idx * 8];
      }
      const unsigned short* vsrcH = VbH + key0;
      const unsigned short* vsrcL = VbL + key0;
      #pragma unroll
      for (int u = 0; u < 2; ++u) {
        int idx = tid + 256 * u;
        int d = idx >> 3, c8 = (idx & 7) * 8;
        *(short8v*)&VtH[d][c8] = *(const short8v*)&vsrcH[(size_t)d * Vrow + c8];
        *(short8v*)&VtL[d][c8] = *(const short8v*)&vsrcL[(size_t)d * Vrow + c8];
      }
    }
    __syncthreads();
    f32x4 S[4] = {};
    #pragma unroll
    for (int kk = 0; kk < 2; ++kk)
      #pragma unroll
      for (int nt = 0; nt < 4; ++nt) {
        short8v kh = *(const short8v*)&KsH[nt * 16 + r16][kk * 32 + g * 8];
        short8v kl = *(const short8v*)&KsL[nt * 16 + r16][kk * 32 + g * 8];
        S[nt] = __builtin_amdgcn_mfma_f32_16x16x32_bf16(qh[kk], kh, S[nt], 0, 0, 0);
        S[nt] = __builtin_amdgcn_mfma_f32_16x16x32_bf16(qh[kk], kl, S[nt], 0, 0, 0);
        S[nt] = __builtin_amdgcn_mfma_f32_16x16x32_bf16(ql[kk], kh, S[nt], 0, 0, 0);
      }
    float tmax[4];
    #pragma unroll
    for (int j = 0; j < 4; ++j)
      tmax[j] = fmaxf(fmaxf(S[0][j], S[1][j]), fmaxf(S[2][j], S[3][j]));
    #pragma unroll
    for (int off = 8; off; off >>= 1)
      #pragma unroll
      for (int j = 0; j < 4; ++j) tmax[j] = fmaxf(tmax[j], __shfl_xor(tmax[j], off));
    float corr[4];
    #pragma unroll
    for (int j = 0; j < 4; ++j) {
      float mn = fmaxf(m[j], tmax[j]);
      corr[j] = expf(m[j] - mn);
      m[j] = mn;
    }
    __syncthreads();
    float tl[4] = {0.f, 0.f, 0.f, 0.f};
    #pragma unroll
    for (int nt = 0; nt < 4; ++nt)
      #pragma unroll
      for (int j = 0; j < 4; ++j) {
        float p = expf(S[nt][j] - m[j]);
        tl[j] += p;
        KsH[wave * 16 + g * 4 + j][nt * 16 + r16] = f2bf(p);   // P hi only
      }
    #pragma unroll
    for (int off = 8; off; off >>= 1)
      #pragma unroll
      for (int j = 0; j < 4; ++j) tl[j] += __shfl_xor(tl[j], off);
    #pragma unroll
    for (int j = 0; j < 4; ++j) lsum[j] = lsum[j] * corr[j] + tl[j];
    #pragma unroll
    for (int nt = 0; nt < 4; ++nt)
      #pragma unroll
      for (int j = 0; j < 4; ++j) O4[nt][j] *= corr[j];
    #pragma unroll
    for (int kk = 0; kk < 2; ++kk) {
      short8v ph = *(const short8v*)&KsH[wave * 16 + r16][kk * 32 + g * 8];
      #pragma unroll
      for (int nt = 0; nt < 4; ++nt) {
        short8v vh = *(const short8v*)&VtH[nt * 16 + r16][kk * 32 + g * 8];
        short8v vl = *(const short8v*)&VtL[nt * 16 + r16][kk * 32 + g * 8];
        O4[nt] = __builtin_amdgcn_mfma_f32_16x16x32_bf16(ph, vh, O4[nt], 0, 0, 0);
        O4[nt] = __builtin_amdgcn_mfma_f32_16x16x32_bf16(ph, vl, O4[nt], 0, 0, 0);
      }
    }
  }
  if (mode == 0) {
    float* Ob = Op + (size_t)b * Osb + (size_t)h * Osh;
    float inv[4];
    #pragma unroll
    for (int j = 0; j < 4; ++j) inv[j] = 1.f / lsum[j];
    #pragma unroll
    for (int nt = 0; nt < 4; ++nt)
      #pragma unroll
      for (int j = 0; j < 4; ++j)
        Ob[(size_t)(q0 + g * 4 + j) * Osr + nt * 16 + r16] = O4[nt][j] * inv[j];
  } else {
    #pragma unroll
    for (int j = 0; j < 4; ++j) {
      size_t rowbase = ((size_t)ch * NBH + bh) * 256 + q0 + g * 4 + j;
      #pragma unroll
      for (int nt = 0; nt < 4; ++nt)
        Opart[rowbase * 64 + nt * 16 + r16] = O4[nt][j];
      if (r16 == 0) { ML[rowbase * 2] = m[j]; ML[rowbase * 2 + 1] = lsum[j]; }
    }
  }
}

// combine NCH chunks -> A3V[bh,256,64]. grid (16, NBH), 256 thr.
__global__ __launch_bounds__(256) void k_flash_comb(const float* __restrict__ Opart,
                                                    const float* __restrict__ ML,
                                                    float* __restrict__ A3V) {
  int jt = blockIdx.x, bh = blockIdx.y;
  int t = threadIdx.x;
  int jr = t >> 4, q16 = t & 15;
  int row = jt * 16 + jr;
  float mv[NCH], lv[NCH];
  float M = -1e30f;
  #pragma unroll
  for (int ch = 0; ch < NCH; ++ch) {
    size_t base = (((size_t)ch * NBH + bh) * 256 + row);
    mv[ch] = ML[base * 2]; lv[ch] = ML[base * 2 + 1];
    M = fmaxf(M, mv[ch]);
  }
  float L = 0.f;
  float4 O = make_float4(0.f, 0.f, 0.f, 0.f);
  #pragma unroll
  for (int ch = 0; ch < NCH; ++ch) {
    float c = expf(mv[ch] - M);
    L += c * lv[ch];
    size_t base = (((size_t)ch * NBH + bh) * 256 + row);
    float4 o = *(const float4*)&Opart[base * 64 + q16 * 4];
    O.x += c * o.x; O.y += c * o.y; O.z += c * o.z; O.w += c * o.w;
  }
  float inv = 1.f / L;
  *(float4*)&A3V[((size_t)bh * 256 + row) * 64 + q16 * 4] =
      make_float4(O.x * inv, O.y * inv, O.z * inv, O.w * inv);
}

// conv over i from Vt hi/lo; grid (NPD/128, NBH), 256 thr.
__global__ __launch_bounds__(256) void k_conv_add(const unsigned short* __restrict__ VtHg,
    const unsigned short* __restrict__ VtLg, const float* __restrict__ cw,
    float* __restrict__ out) {
  int it = blockIdx.x, bh = blockIdx.y;
  int b = bh >> 3, h = bh & 7;
  int i0 = it * 128;
  int t = threadIdx.x;
  __shared__ float Vs[64][161];
  const unsigned short* vh = VtHg + (size_t)bh * 64 * NPD;
  const unsigned short* vl = VtLg + (size_t)bh * 64 * NPD;
  for (int u = 0; u < 40; ++u) {
    int idx = t + 256 * u;
    int d = idx / 160, ii = idx - d * 160;
    int gi = i0 - 16 + ii;
    float v = 0.f;
    if (gi >= 0 && gi < NPD) {
      size_t a = (size_t)d * NPD + gi;
      v = bf2f(vh[a]) + bf2f(vl[a]);
    }
    Vs[d][ii] = v;
  }
  __syncthreads();
  float w[CONVK];
  #pragma unroll
  for (int p = 0; p < CONVK; ++p) w[p] = cw[h * CONVK + p];
  int rgrp = t >> 6, d = t & 63;
  for (int r = rgrp * 32; r < rgrp * 32 + 32; ++r) {
    float acc = 0.f;
    #pragma unroll
    for (int p = 0; p < CONVK; ++p) acc += w[p] * Vs[d][r + p];
    out[((size_t)b * NPD + i0 + r) * 512 + h * 64 + d] += acc;
  }
}

__global__ void k_out_write(const float* __restrict__ H, float* __restrict__ out) {
  size_t n0 = (size_t)BATCH * 512;
  size_t total = n0 + (size_t)BATCH * (NTOK - 1) * 512;
  for (size_t idx = (size_t)blockIdx.x * blockDim.x + threadIdx.x; idx < total;
       idx += (size_t)gridDim.x * blockDim.x) {
    float v;
    if (idx < n0) {
      int b = (int)(idx >> 9); int d = (int)(idx & 511);
      v = H[((size_t)b * NTOK) * 512 + d];
    } else {
      size_t r = idx - n0;
      size_t bj = r >> 9; int d = (int)(r & 511);
      int b = (int)(bj / (NTOK - 1)); int j = (int)(bj % (NTOK - 1));
      v = H[((size_t)b * NTOK + 1 + j) * 512 + d];
    }
    out[idx] = v;
  }
}

// ============================ host ============================

extern "C" void kernel_launch(void* const* d_in, const int* in_sizes, int n_in,
                              void* d_out, int out_size, void* d_ws, size_t ws_size,
                              hipStream_t stream) {
  (void)in_sizes; (void)n_in;

  const float* feat = (const float*)d_in[0];
  const float* cls  = (const float*)d_in[1];
  const float* m1_gw = (const float*)d_in[2];  const float* m1_gb = (const float*)d_in[3];
  const float* m1_f1w = (const float*)d_in[4]; const float* m1_f1b = (const float*)d_in[5];
  const float* m1_l1g = (const float*)d_in[6]; const float* m1_l1b = (const float*)d_in[7];
  const float* m1_f2w = (const float*)d_in[8]; const float* m1_f2b = (const float*)d_in[9];
  const float* m1_l2g = (const float*)d_in[10]; const float* m1_l2b = (const float*)d_in[11];
  const float* m2_gw = (const float*)d_in[12]; const float* m2_gb = (const float*)d_in[13];
  const float* m2_f1w = (const float*)d_in[14]; const float* m2_f1b = (const float*)d_in[15];
  const float* m2_l1g = (const float*)d_in[16]; const float* m2_l1b = (const float*)d_in[17];
  const float* m2_f2w = (const float*)d_in[18]; const float* m2_f2b = (const float*)d_in[19];
  const float* m2_l2g = (const float*)d_in[20]; const float* m2_l2b = (const float*)d_in[21];
  const float* l1_ng = (const float*)d_in[22]; const float* l1_nb = (const float*)d_in[23];
  const float* l1_qkvw = (const float*)d_in[24]; const float* l1_outw = (const float*)d_in[25];
  const float* l1_outb = (const float*)d_in[26]; const float* l1_convw = (const float*)d_in[27];
  const float* l2_ng = (const float*)d_in[28]; const float* l2_nb = (const float*)d_in[29];
  const float* l2_qkvw = (const float*)d_in[30]; const float* l2_outw = (const float*)d_in[31];
  const float* l2_outb = (const float*)d_in[32]; const float* l2_convw = (const float*)d_in[33];

  // ---- workspace layout (units: fp32 elements) ----
  constexpr size_t SZ_H    = (size_t)BN_TOK * 512;
  constexpr size_t SZ_ROW  = (size_t)RPAD * 512;
  float* W = (float*)d_ws;
  float* H  = W;
  float* WT = W + SZ_H;
  unsigned int* SC = (unsigned int*)(W + SZ_H + 97360);
  float* pool = W + SZ_H + 97360 + 16;

  float* R2 = pool;                    // XLn -> AttnO ; MoE T1
  float* R3 = pool + SZ_ROW;           // Vr hi/lo -> K hi/lo -> Qb ; MoE T2
  float* R4 = pool + 2 * SZ_ROW;       // Vt hi/lo ; MoE Xsnap
  float* SMALL = pool + 3 * SZ_ROW;
  float* Xm  = SMALL;                  // 524288; later ML for flash3
  float* QL  = SMALL + 524288;
  float* KL  = SMALL + 1048576;
  float* A2  = SMALL + 1572864;        // 2.1M; MoE: Bt + token lists; post-pinv: KLH/...
  float* Zb  = SMALL + 3670016;        // pinv Y; post-pinv: Opart (spans Zb+XZp)
  float* XZp = SMALL + 5767168;        // pinv F1
  float* Wa  = SMALL + 7864320;        // pinv F2; post-pinv: qkv/out weight Bt
  float* Wb  = SMALL + 9961472;        // pinv Z (z_final)
  float* A3V = SMALL + 12058624;
  float* W2b = SMALL + 12582912;
  size_t total_f = (SZ_H + 97360 + 16) + 3 * SZ_ROW + 13107200;
  if (total_f * 4 > ws_size) {
    k_diag_fill<<<2048, 256, 0, stream>>>((float*)d_out, (size_t)out_size,
                                          (float)(ws_size >> 20));
    return;
  }

  k_build_h<<<2048, 256, 0, stream>>>(feat, cls, H);

  auto run_moe = [&](const float* gw, const float* gb, const float* f1w, const float* f1b,
                     const float* l1g, const float* l1b, const float* f2w, const float* f2b,
                     const float* l2g, const float* l2b, int E, int k) {
    float* T1 = R2; float* T2 = R3; float* Xsnap = R4;
    unsigned short* BtHi = (unsigned short*)A2;
    unsigned short* BtLo = (unsigned short*)(A2 + 131072);
    int* LISTS = (int*)(A2 + 262144);            // E x LISTCAP ints
    int* CNT = (int*)(SC + 4);                   // 4 ints
    hipMemcpyAsync(Xsnap, H, SZ_H * 4, hipMemcpyDeviceToDevice, stream);
    hipMemsetAsync(CNT, 0, 4 * sizeof(int), stream);
    k_gate<<<BN_TOK, 64, 0, stream>>>(H, gw, gb, WT, E, k);
    k_lists<<<(BN_TOK + 63) / 64, 64, 0, stream>>>(WT, CNT, LISTS, E);
    dim3 g(4, (BN_TOK + 127) / 128, 1);
    for (int e = 0; e < E; ++e) {
      const int* lst = LISTS + (size_t)e * LISTCAP;
      const int* cnt = CNT + e;
      k_wconv<<<dim3(8, 8), 256, 0, stream>>>(f1w + (size_t)e * 262144, 512, BtHi, BtLo);
      k_gemm_mfma<<<g, 256, 0, stream>>>(Xsnap, BtHi, BtLo, f1b + e * 512, T1,
          BN_TOK, 512, 512, 1.f, 0, nullptr, lst, cnt);
      k_ln_relu_g<<<BN_TOK, 64, 0, stream>>>(T1, l1g + e * 512, l1b + e * 512, lst, cnt);
      k_wconv<<<dim3(8, 8), 256, 0, stream>>>(f2w + (size_t)e * 262144, 512, BtHi, BtLo);
      k_gemm_mfma<<<g, 256, 0, stream>>>(T1, BtHi, BtLo, f2b + e * 512, T2,
          BN_TOK, 512, 512, 1.f, 0, nullptr, lst, cnt);
      k_ln_waccum<<<BN_TOK, 64, 0, stream>>>(T2, H, l2g + e * 512, l2b + e * 512, WT, e);
    }
  };

  auto run_attn = [&](const float* ng, const float* nb, const float* qkvw, const float* outw,
                      const float* outb, const float* convw) {
    float* XLn = R2; float* AttnO = R2;
    float* Qb = R3;
    unsigned short* VrH = (unsigned short*)R3;
    unsigned short* VrL = VrH + 12582912;
    unsigned short* KH  = (unsigned short*)R3;
    unsigned short* KLo = KH + 12582912;
    unsigned short* VtH = (unsigned short*)R4;
    unsigned short* VtL = VtH + 12582912;
    k_ln_pad<<<RPAD, 64, 0, stream>>>(H, XLn, ng, nb);
    k_xmean<<<BATCH * 256, 512, 0, stream>>>(XLn, Xm);
    k_gemm<<<dim3(8, 16, 1), 256, 0, stream>>>(Xm, qkvw, nullptr, QL,
        1024, 512, 512, 512, 1536, 512, 0, 0, 0, 0.125f, 0, 0.f);
    k_gemm<<<dim3(8, 16, 1), 256, 0, stream>>>(Xm, qkvw + 512, nullptr, KL,
        1024, 512, 512, 512, 1536, 512, 0, 0, 0, 1.f, 0, 0.f);
    k_attn2<<<NBH * 256, 256, 0, stream>>>(QL, KL, A2);
    hipMemsetAsync(SC, 0, 8, stream);
    k_pinv_scalars<<<NBH, 256, 0, stream>>>(A2, SC);
    // ---- pinv Newton-Schulz, transposed world; cheap (hi-only) early iterations ----
    k_y0<<<2048, 256, 0, stream>>>(A2, Zb, SC);      // Y = z^T
    k_zinit<<<2048, 256, 0, stream>>>(A2, Wb, SC);   // Z = z
    float* Y = Zb; float* Z = Wb; float* F1 = XZp; float* F2 = Wa;
    dim3 gq(2, 2, NBH);
    for (int it = 0; it < 6; ++it) {
      int np = (it < 4) ? 1 : 3;
      k_gemm_mfma2<<<gq, 256, 0, stream>>>(A2, Y, F1, 1.f, 0, 0.f, 0, np);      // F1 = XZ
      k_tpose<<<dim3(4, 4, NBH), 256, 0, stream>>>(F1, F2);                     // F2 = XZT
      k_gemm_mfma2<<<gq, 256, 0, stream>>>(F2, F1, Y, 1.f, 5, 15.f, 1, np);     // Y = QT
      k_gemm_mfma2<<<gq, 256, 0, stream>>>(Y, F1, F2, 1.f, 5, 13.f, 0, np);     // F2 = PT
      k_gemm_mfma2<<<gq, 256, 0, stream>>>(Z, F2, F1, 0.25f, 0, 0.f, 0, np);    // F1 = z_new
      float* tz = Z; Z = F1; F1 = tz;
      if (it < 5)
        k_tpose<<<dim3(4, 4, NBH), 256, 0, stream>>>(Z, Y);                     // Y = z^T
    }
    // z_final in Z. A2/Zb/XZp/Wa now dead (except Z's current buffer).
    unsigned short* KLH = (unsigned short*)A2;
    unsigned short* KLL = KLH + 524288;
    unsigned short* W2tH = KLH + 1048576;
    unsigned short* W2tL = KLH + 1572864;
    k_cvt_kl<<<2048, 256, 0, stream>>>(KL, KLH, KLL);
    unsigned short* BtQH = (unsigned short*)Wa;
    unsigned short* BtQL = BtQH + 786432;
    k_wconv<<<dim3(24, 8), 256, 0, stream>>>(qkvw, 1536, BtQH, BtQL);
    dim3 gr(4, (RPAD + 127) / 128, 1);
    // V projection -> hi/lo packed per-head in R3; transpose -> R4
    k_gemm_mfma<<<gr, 256, 0, stream>>>(XLn, BtQH + 1024 * 512, BtQL + 1024 * 512, nullptr,
        (float*)VrH, RPAD, 512, 512, 1.f, 6, VrL, nullptr, nullptr);
    k_vtpose<<<dim3(NPD / 64, NBH), 256, 0, stream>>>(VrH, VrL, VtH, VtL);
    // K projection -> hi/lo packed in R3 (Vr dead)
    k_gemm_mfma<<<gr, 256, 0, stream>>>(XLn, BtQH + 512 * 512, BtQL + 512 * 512, nullptr,
        (float*)KH, RPAD, 512, 512, 1.f, 6, KLo, nullptr, nullptr);
    // attn3: split-kv flash; Opart in Zb..XZp (4.19M), ML in Xm
    k_flash_pre<<<dim3(4, NBH, NCH), 256, 0, stream>>>(
        QL, 131072LL, 64LL, 512,
        KH, KLo, (long long)NPD * 64,
        VtH, VtL, (long long)64 * NPD, NPD,
        nullptr, 0, 0, 0, Zb, Xm, NPD / (64 * NCH), 1);
    k_flash_comb<<<dim3(16, NBH), 256, 0, stream>>>(Zb, Xm, A3V);
    // W2b[bh] = z_final @ A3V
    k_gemm<<<dim3(1, 4, NBH), 256, 0, stream>>>(Z, A3V, nullptr, W2b,
        256, 64, 256, 256, 64, 64, 65536, 16384, 16384, 1.f, 0, 0.f);
    k_cvt_w2t<<<2048, 256, 0, stream>>>(W2b, W2tH, W2tL);
    // Q projection (scaled) -> fp32 R3 (K dead after flash3)
    k_gemm_mfma<<<gr, 256, 0, stream>>>(XLn, BtQH, BtQL, nullptr,
        Qb, RPAD, 512, 512, 0.125f, 0, nullptr, nullptr, nullptr);
    // attn1 flash -> AttnO (over XLn, dead after Q proj)
    k_flash_pre<<<dim3(NPD / 64, NBH, 1), 256, 0, stream>>>(
        Qb, (long long)NPD * 512, 64LL, 512,
        KLH, KLL, 16384LL,
        W2tH, W2tL, 16384LL, 256,
        AttnO, (long long)NPD * 512, 64LL, 512,
        nullptr, nullptr, 4, 0);
    k_conv_add<<<dim3(NPD / 128, NBH), 256, 0, stream>>>(VtH, VtL, convw, AttnO);
    // out-proj, cropped + accumulated into H (Bt in Wa, dead)
    unsigned short* BtOH = (unsigned short*)Wa;
    unsigned short* BtOL = BtOH + 262144;
    k_wconv<<<dim3(8, 8), 256, 0, stream>>>(outw, 512, BtOH, BtOL);
    k_gemm_mfma<<<gr, 256, 0, stream>>>(AttnO, BtOH, BtOL, outb,
        H, RPAD, 512, 512, 1.f, 2, nullptr, nullptr, nullptr);
  };

  run_moe(m1_gw, m1_gb, m1_f1w, m1_f1b, m1_l1g, m1_l1b, m1_f2w, m1_f2b, m1_l2g, m1_l2b, 2, 1);
  run_attn(l1_ng, l1_nb, l1_qkvw, l1_outw, l1_outb, l1_convw);
  run_moe(m2_gw, m2_gb, m2_f1w, m2_f1b, m2_l1g, m2_l1b, m2_f2w, m2_f2b, m2_l2g, m2_l2b, 4, 2);
  run_attn(l2_ng, l2_nb, l2_qkvw, l2_outw, l2_outb, l2_convw);

  k_out_write<<<2048, 256, 0, stream>>>(H, (float*)d_out);
}

// Round 17
// 3611.415 us; speedup vs baseline: 1.0454x; 1.0454x over previous
//
#include <hip/hip_runtime.h>
#include <hip/hip_bf16.h>

// ---- problem constants ----
constexpr int BATCH = 4;
constexpr int NTOK  = 6085;            // 1 cls + 6084 (wrap-padded to 78^2)
constexpr int BN_TOK = BATCH * NTOK;   // 24340
constexpr int NPD   = 6144;            // 6085 front-padded to multiple of 256
constexpr int RPAD  = BATCH * NPD;     // 24576
constexpr int DMODEL = 512;
constexpr int NH = 8, DH = 64;
constexpr int NBH = BATCH * NH;        // 32
constexpr int LGRP = NPD / 256;        // 24 tokens per landmark
constexpr int PAD_FRONT = 59;
constexpr int CONVK = 33;
constexpr int NCH = 8;                 // attn3 kv chunks
constexpr int LISTCAP = 24576;         // per-expert token list capacity

typedef __attribute__((ext_vector_type(8))) short short8v;
typedef __attribute__((ext_vector_type(4))) float f32x4;

__device__ __forceinline__ unsigned short f2bf(float f) {
  unsigned u = __float_as_uint(f);
  u += 0x7FFF + ((u >> 16) & 1);
  return (unsigned short)(u >> 16);
}
__device__ __forceinline__ float bf2f(unsigned short h) {
  return __uint_as_float((unsigned)h << 16);
}

// ============================ kernels ============================

__global__ void k_build_h(const float* __restrict__ feat, const float* __restrict__ cls,
                          float* __restrict__ H) {
  size_t total = (size_t)BN_TOK * DMODEL;
  for (size_t idx = (size_t)blockIdx.x * blockDim.x + threadIdx.x; idx < total;
       idx += (size_t)gridDim.x * blockDim.x) {
    int d = (int)(idx & 511);
    size_t tok = idx >> 9;
    int b = (int)(tok / NTOK), n = (int)(tok % NTOK);
    float v;
    if (n == 0) v = cls[d];
    else {
      int i = n - 1; if (i >= 6000) i -= 6000;
      v = feat[((size_t)b * 6000 + i) * DMODEL + d];
    }
    H[idx] = v;
  }
}

__global__ void k_diag_fill(float* __restrict__ out, size_t n, float val) {
  for (size_t i = (size_t)blockIdx.x * blockDim.x + threadIdx.x; i < n;
       i += (size_t)gridDim.x * blockDim.x)
    out[i] = val;
}

// weight convert: W fp32 [512][ldb] (use N cols) -> hi/lo bf16 [N][512] (transposed)
// batched over blockIdx.z (expert): W += z*wstride, hi/lo += z*hstride
__global__ __launch_bounds__(256) void k_wconv(const float* __restrict__ W, int ldb,
    long long wstride, unsigned short* __restrict__ hi, unsigned short* __restrict__ lo,
    long long hstride) {
  __shared__ unsigned short Th[64][80], Tl[64][80];
  int z = blockIdx.z;
  W  += (size_t)z * (size_t)wstride;
  hi += (size_t)z * (size_t)hstride;
  lo += (size_t)z * (size_t)hstride;
  int bk = blockIdx.y * 64, bn = blockIdx.x * 64;
  int t = threadIdx.x;
  int kr = t >> 2, cq = (t & 3) * 16;
  const float* src = W + (size_t)(bk + kr) * ldb + bn + cq;
  #pragma unroll
  for (int q = 0; q < 4; ++q) {
    float4 v = *(const float4*)(src + q * 4);
    float vs[4] = {v.x, v.y, v.z, v.w};
    #pragma unroll
    for (int e = 0; e < 4; ++e) {
      int n = cq + q * 4 + e;
      unsigned short h = f2bf(vs[e]);
      Th[n][kr] = h;
      Tl[n][kr] = f2bf(vs[e] - bf2f(h));
    }
  }
  __syncthreads();
  int nr = t >> 2, kq = (t & 3) * 16;
  size_t o = (size_t)(bn + nr) * 512 + bk + kq;
  *(short8v*)&hi[o]     = *(const short8v*)&Th[nr][kq];
  *(short8v*)&hi[o + 8] = *(const short8v*)&Th[nr][kq + 8];
  *(short8v*)&lo[o]     = *(const short8v*)&Tl[nr][kq];
  *(short8v*)&lo[o + 8] = *(const short8v*)&Tl[nr][kq + 8];
}

// per-expert token list build: wave ballot compaction, grouped atomic base.
__global__ void k_lists(const float* __restrict__ WT, int* __restrict__ cnt,
                        int* __restrict__ lists, int E) {
  int lane = threadIdx.x;
  int tok = blockIdx.x * 64 + lane;
  for (int e = 0; e < E; ++e) {
    bool sel = (tok < BN_TOK) && (WT[(size_t)tok * 4 + e] != 0.f);
    unsigned long long mask = __ballot(sel);
    int rank = __popcll(mask & ((1ull << lane) - 1ull));
    int n = __popcll(mask);
    int base = 0;
    if (lane == 0 && n > 0) base = atomicAdd(&cnt[e], n);
    base = __shfl(base, 0);
    if (sel) lists[(size_t)e * LISTCAP + base + rank] = tok;
  }
}

// ---- bf16x3 MFMA GEMM: C = alpha*(A@B)+bias. A fp32 [M][lda] (in-kernel split),
// Bt hi/lo bf16 [N][512]. In-loop loads + XCD-chunked block swizzle.
// Optional row gather/scatter: rowidx/cnt (per-expert MoE token lists).
// omode 0: fp32 C; 2: resid-accum crop pad; 3: head-split fp32; 6: head-split hi/lo
__global__ __launch_bounds__(256) void k_gemm_mfma(const float* __restrict__ A,
    const unsigned short* __restrict__ BtH, const unsigned short* __restrict__ BtL,
    const float* __restrict__ bias, float* __restrict__ C,
    int M, int lda, int ldc, float alpha, int omode, unsigned short* __restrict__ Clo,
    const int* __restrict__ rowidx, const int* __restrict__ cnt)
{
  __shared__ unsigned short AsH[128][40], AsL[128][40];
  __shared__ unsigned short BsH[128][40], BsL[128][40];
  // XCD-chunked bijective block swizzle (m204 form)
  int nwg = gridDim.x * gridDim.y;
  int wid = blockIdx.y * gridDim.x + blockIdx.x;
  int qq = nwg >> 3, rr = nwg & 7;
  int xcd = wid & 7, pos = wid >> 3;
  int Lid = (xcd < rr ? xcd * (qq + 1) : rr * (qq + 1) + (xcd - rr) * qq) + pos;
  int bn = (Lid % gridDim.x) * 128;
  int bm = (Lid / gridDim.x) * 128;
  int Mv = M;
  if (cnt) { Mv = *cnt; if (Mv > M) Mv = M; }
  if (bm >= Mv) return;
  int tid = threadIdx.x;
  int wave = tid >> 6, lane = tid & 63;
  int mo = (wave >> 1) * 64, no = (wave & 1) * 64;
  int r16 = lane & 15, g = lane >> 4;
  f32x4 acc[4][4] = {};
  int srow = tid >> 1, shalf = (tid & 1) * 16;
  int lrow = bm + srow;
  bool avalid = lrow < Mv;
  int arow = lrow;
  if (rowidx && avalid) arow = rowidx[lrow];
  if (!avalid) arow = 0;
  const float* aptr = A + (size_t)arow * lda + shalf;
  const unsigned short* bhptr = BtH + (size_t)(bn + srow) * 512 + shalf;
  const unsigned short* blptr = BtL + (size_t)(bn + srow) * 512 + shalf;
  for (int k0 = 0; k0 < 512; k0 += 32) {
    unsigned short h8[16], l8[16];
    #pragma unroll
    for (int q = 0; q < 4; ++q) {
      float4 v = avalid ? *(const float4*)(aptr + k0 + q * 4) : make_float4(0.f, 0.f, 0.f, 0.f);
      float vs[4] = {v.x, v.y, v.z, v.w};
      #pragma unroll
      for (int e = 0; e < 4; ++e) {
        unsigned short hh = f2bf(vs[e]);
        h8[q * 4 + e] = hh;
        l8[q * 4 + e] = f2bf(vs[e] - bf2f(hh));
      }
    }
    *(short8v*)&AsH[srow][shalf]     = *(short8v*)&h8[0];
    *(short8v*)&AsH[srow][shalf + 8] = *(short8v*)&h8[8];
    *(short8v*)&AsL[srow][shalf]     = *(short8v*)&l8[0];
    *(short8v*)&AsL[srow][shalf + 8] = *(short8v*)&l8[8];
    *(short8v*)&BsH[srow][shalf]     = *(const short8v*)(bhptr + k0);
    *(short8v*)&BsH[srow][shalf + 8] = *(const short8v*)(bhptr + k0 + 8);
    *(short8v*)&BsL[srow][shalf]     = *(const short8v*)(blptr + k0);
    *(short8v*)&BsL[srow][shalf + 8] = *(const short8v*)(blptr + k0 + 8);
    __syncthreads();
    short8v ah[4], al[4], bh[4], bl[4];
    #pragma unroll
    for (int mt = 0; mt < 4; ++mt) {
      ah[mt] = *(const short8v*)&AsH[mo + mt * 16 + r16][g * 8];
      al[mt] = *(const short8v*)&AsL[mo + mt * 16 + r16][g * 8];
    }
    #pragma unroll
    for (int nt = 0; nt < 4; ++nt) {
      bh[nt] = *(const short8v*)&BsH[no + nt * 16 + r16][g * 8];
      bl[nt] = *(const short8v*)&BsL[no + nt * 16 + r16][g * 8];
    }
    #pragma unroll
    for (int mt = 0; mt < 4; ++mt)
      #pragma unroll
      for (int nt = 0; nt < 4; ++nt) {
        acc[mt][nt] = __builtin_amdgcn_mfma_f32_16x16x32_bf16(ah[mt], bh[nt], acc[mt][nt], 0, 0, 0);
        acc[mt][nt] = __builtin_amdgcn_mfma_f32_16x16x32_bf16(ah[mt], bl[nt], acc[mt][nt], 0, 0, 0);
        acc[mt][nt] = __builtin_amdgcn_mfma_f32_16x16x32_bf16(al[mt], bh[nt], acc[mt][nt], 0, 0, 0);
      }
    __syncthreads();
  }
  #pragma unroll
  for (int mt = 0; mt < 4; ++mt)
    #pragma unroll
    for (int nt = 0; nt < 4; ++nt)
      #pragma unroll
      for (int j = 0; j < 4; ++j) {
        int lr = bm + mo + mt * 16 + g * 4 + j;
        int gc = bn + no + nt * 16 + r16;
        if (lr >= Mv) continue;
        int gr = rowidx ? rowidx[lr] : lr;
        float v = alpha * acc[mt][nt][j] + (bias ? bias[gc] : 0.f);
        if (omode == 0) {
          C[(size_t)gr * ldc + gc] = v;
        } else if (omode == 2) {
          int bb = gr / NPD, ii = gr % NPD;
          if (ii >= PAD_FRONT)
            C[((size_t)bb * NTOK + ii - PAD_FRONT) * 512 + gc] += v;
        } else if (omode == 3) {
          int bb = gr / NPD, ii = gr % NPD;
          int hh = gc >> 6, dd = gc & 63;
          C[(((size_t)bb * NH + hh) * NPD + ii) * 64 + dd] = v;
        } else {  // omode 6: packed head-split hi/lo
          int bb = gr / NPD, ii = gr % NPD;
          int hh = gc >> 6, dd = gc & 63;
          size_t idx = (((size_t)bb * NH + hh) * NPD + ii) * 64 + dd;
          unsigned short hi = f2bf(v);
          ((unsigned short*)C)[idx] = hi;
          Clo[idx] = f2bf(v - bf2f(hi));
        }
      }
}

// ---- bf16 MFMA GEMM, both fp32, batched 256x256x256 (pinv). nprod=1 or 3 ----
// Ct (optional): also write transposed result (fused k_tpose).
__global__ __launch_bounds__(256) void k_gemm_mfma2(const float* __restrict__ A,
    const float* __restrict__ Bt, float* __restrict__ C,
    float alpha, int omode, float cdiag, int premap, int nprod, float* __restrict__ Ct)
{
  __shared__ unsigned short AsH[128][40], AsL[128][40];
  __shared__ unsigned short BsH[128][40], BsL[128][40];
  size_t zo = (size_t)blockIdx.z * 65536;
  int bm = blockIdx.y * 128, bn = blockIdx.x * 128;
  int tid = threadIdx.x;
  int wave = tid >> 6, lane = tid & 63;
  int mo = (wave >> 1) * 64, no = (wave & 1) * 64;
  int r16 = lane & 15, g = lane >> 4;
  f32x4 acc[4][4] = {};
  int srow = tid >> 1, shalf = (tid & 1) * 16;
  int grow = bm + srow;
  int gn = bn + srow;
  for (int k0 = 0; k0 < 256; k0 += 32) {
    unsigned short h8[16], l8[16];
    #pragma unroll
    for (int q = 0; q < 4; ++q) {
      float4 v = *(const float4*)&A[zo + (size_t)grow * 256 + k0 + shalf + q * 4];
      float vs[4] = {v.x, v.y, v.z, v.w};
      #pragma unroll
      for (int e = 0; e < 4; ++e) {
        float a = vs[e];
        if (premap) a = ((grow == (k0 + shalf + q * 4 + e)) ? 7.f : 0.f) - a;
        unsigned short hh = f2bf(a);
        h8[q * 4 + e] = hh;
        l8[q * 4 + e] = (nprod == 3) ? f2bf(a - bf2f(hh)) : (unsigned short)0;
      }
    }
    *(short8v*)&AsH[srow][shalf]     = *(short8v*)&h8[0];
    *(short8v*)&AsH[srow][shalf + 8] = *(short8v*)&h8[8];
    *(short8v*)&AsL[srow][shalf]     = *(short8v*)&l8[0];
    *(short8v*)&AsL[srow][shalf + 8] = *(short8v*)&l8[8];
    #pragma unroll
    for (int q = 0; q < 4; ++q) {
      float4 v = *(const float4*)&Bt[zo + (size_t)gn * 256 + k0 + shalf + q * 4];
      float vs[4] = {v.x, v.y, v.z, v.w};
      #pragma unroll
      for (int e = 0; e < 4; ++e) {
        unsigned short hh = f2bf(vs[e]);
        h8[q * 4 + e] = hh;
        l8[q * 4 + e] = (nprod == 3) ? f2bf(vs[e] - bf2f(hh)) : (unsigned short)0;
      }
    }
    *(short8v*)&BsH[srow][shalf]     = *(short8v*)&h8[0];
    *(short8v*)&BsH[srow][shalf + 8] = *(short8v*)&h8[8];
    *(short8v*)&BsL[srow][shalf]     = *(short8v*)&l8[0];
    *(short8v*)&BsL[srow][shalf + 8] = *(short8v*)&l8[8];
    __syncthreads();
    short8v ah[4], al[4], bh[4], bl[4];
    #pragma unroll
    for (int mt = 0; mt < 4; ++mt) {
      ah[mt] = *(const short8v*)&AsH[mo + mt * 16 + r16][g * 8];
      al[mt] = *(const short8v*)&AsL[mo + mt * 16 + r16][g * 8];
    }
    #pragma unroll
    for (int nt = 0; nt < 4; ++nt) {
      bh[nt] = *(const short8v*)&BsH[no + nt * 16 + r16][g * 8];
      bl[nt] = *(const short8v*)&BsL[no + nt * 16 + r16][g * 8];
    }
    #pragma unroll
    for (int mt = 0; mt < 4; ++mt)
      #pragma unroll
      for (int nt = 0; nt < 4; ++nt) {
        acc[mt][nt] = __builtin_amdgcn_mfma_f32_16x16x32_bf16(ah[mt], bh[nt], acc[mt][nt], 0, 0, 0);
        if (nprod == 3) {
          acc[mt][nt] = __builtin_amdgcn_mfma_f32_16x16x32_bf16(ah[mt], bl[nt], acc[mt][nt], 0, 0, 0);
          acc[mt][nt] = __builtin_amdgcn_mfma_f32_16x16x32_bf16(al[mt], bh[nt], acc[mt][nt], 0, 0, 0);
        }
      }
    __syncthreads();
  }
  #pragma unroll
  for (int mt = 0; mt < 4; ++mt)
    #pragma unroll
    for (int nt = 0; nt < 4; ++nt) {
      float tv[4];
      int gr0 = bm + mo + mt * 16 + g * 4;
      int gc = bn + no + nt * 16 + r16;
      #pragma unroll
      for (int j = 0; j < 4; ++j) {
        int gr = gr0 + j;
        float v;
        if (omode == 5) v = ((gr == gc) ? cdiag : 0.f) - acc[mt][nt][j];
        else            v = alpha * acc[mt][nt][j];
        C[zo + (size_t)gr * 256 + gc] = v;
        tv[j] = v;
      }
      if (Ct) *(float4*)&Ct[zo + (size_t)gc * 256 + gr0] = *(float4*)&tv[0];
    }
}

// fused y0 + zinit: Y = A2*scale, Z = A2^T*scale
__global__ void k_yz0(const float* __restrict__ A2, float* __restrict__ Y,
                      float* __restrict__ Z, const unsigned int* __restrict__ sc) {
  float scale = 1.f / (__uint_as_float(sc[0]) * __uint_as_float(sc[1]));
  size_t total = (size_t)NBH * 65536;
  for (size_t idx = (size_t)blockIdx.x * blockDim.x + threadIdx.x; idx < total;
       idx += (size_t)gridDim.x * blockDim.x) {
    size_t bh = idx >> 16; int r = (int)((idx >> 8) & 255); int cc = (int)(idx & 255);
    Y[idx] = A2[idx] * scale;
    Z[idx] = A2[(bh << 16) + (size_t)cc * 256 + r] * scale;
  }
}

// --- 64x64-tile fp32 GEMM (small/batched shapes) ---
// omode 0: C = alpha*(A@B)+bias ; 5: cdiag*I-(A@B) ; 7: QL|KL split (alpha per half)
__global__ __launch_bounds__(256) void k_gemm(const float* __restrict__ A,
    const float* __restrict__ B,
    const float* __restrict__ bias, float* __restrict__ C,
    int M, int N, int K, int lda, int ldb, int ldc,
    long long sA, long long sB, long long sC, float alpha, int omode, float cdiag)
{
  __shared__ float As[16][65];
  __shared__ float Bs[16][65];
  int z = blockIdx.z;
  A += (size_t)z * (size_t)sA;
  B += (size_t)z * (size_t)sB;
  int bm = blockIdx.y * 64, bn = blockIdx.x * 64;
  int tid = threadIdx.x;
  int tr = tid >> 4, tc = tid & 15;
  int ar = tid >> 2, aq = tid & 3;
  int br = tid >> 4, bq = tid & 15;
  float acc[4][4] = {};
  for (int k0 = 0; k0 < K; k0 += 16) {
    {
      int gr = bm + ar;
      float4 v = make_float4(0.f, 0.f, 0.f, 0.f);
      if (gr < M) v = *(const float4*)&A[(size_t)gr * lda + k0 + aq * 4];
      As[aq * 4 + 0][ar] = v.x; As[aq * 4 + 1][ar] = v.y;
      As[aq * 4 + 2][ar] = v.z; As[aq * 4 + 3][ar] = v.w;
    }
    {
      float4 v = *(const float4*)&B[(size_t)(k0 + br) * ldb + bn + bq * 4];
      Bs[br][bq * 4 + 0] = v.x; Bs[br][bq * 4 + 1] = v.y;
      Bs[br][bq * 4 + 2] = v.z; Bs[br][bq * 4 + 3] = v.w;
    }
    __syncthreads();
    #pragma unroll
    for (int kk = 0; kk < 16; ++kk) {
      float a[4], bv[4];
      #pragma unroll
      for (int i = 0; i < 4; ++i) a[i] = As[kk][tr * 4 + i];
      #pragma unroll
      for (int j = 0; j < 4; ++j) bv[j] = Bs[kk][tc * 4 + j];
      #pragma unroll
      for (int i = 0; i < 4; ++i)
        #pragma unroll
        for (int j = 0; j < 4; ++j) acc[i][j] += a[i] * bv[j];
    }
    __syncthreads();
  }
  #pragma unroll
  for (int i = 0; i < 4; ++i) {
    int gr = bm + tr * 4 + i;
    if (gr >= M) continue;
    #pragma unroll
    for (int j = 0; j < 4; ++j) {
      int gc = bn + tc * 4 + j;
      if (omode == 7) {
        float v = ((gc < 512) ? 0.125f : 1.f) * acc[i][j];
        if (gc < 512) C[(size_t)gr * 512 + gc] = v;
        else          C[524288 + (size_t)gr * 512 + (gc - 512)] = v;
      } else if (omode == 5) {
        C[(size_t)z * (size_t)sC + (size_t)gr * ldc + gc] =
            ((gr == gc) ? cdiag : 0.f) - acc[i][j];
      } else {
        C[(size_t)z * (size_t)sC + (size_t)gr * ldc + gc] =
            alpha * acc[i][j] + (bias ? bias[gc] : 0.f);
      }
    }
  }
}

// gate scores + top-k softmax weights
__global__ void k_gate(const float* __restrict__ X, const float* __restrict__ gw,
                       const float* __restrict__ gb, float* __restrict__ WT, int E, int k) {
  int tok = blockIdx.x; int lane = threadIdx.x;
  const float* x = X + (size_t)tok * DMODEL;
  float s[4] = {0.f, 0.f, 0.f, 0.f};
  for (int d = lane; d < DMODEL; d += 64) {
    float xv = x[d];
    for (int e = 0; e < E; ++e) s[e] += xv * gw[(size_t)d * E + e];
  }
  #pragma unroll
  for (int off = 32; off; off >>= 1) {
    #pragma unroll
    for (int e = 0; e < 4; ++e) s[e] += __shfl_down(s[e], off);
  }
  if (lane == 0) {
    for (int e = 0; e < E; ++e) s[e] += gb[e];
    float w[4] = {0.f, 0.f, 0.f, 0.f};
    int i1 = 0;
    for (int e = 1; e < E; ++e) if (s[e] > s[i1]) i1 = e;
    if (k == 1) {
      w[i1] = 1.f;
    } else {
      int i2 = -1;
      for (int e = 0; e < E; ++e) { if (e == i1) continue; if (i2 < 0 || s[e] > s[i2]) i2 = e; }
      float e2 = expf(s[i2] - s[i1]);
      float zz = 1.f + e2;
      w[i1] = 1.f / zz; w[i2] = e2 / zz;
    }
    #pragma unroll
    for (int e = 0; e < 4; ++e) WT[(size_t)tok * 4 + e] = w[e];
  }
}

__device__ __forceinline__ void wave_ln_stats(const float* x, int lane, float& mu, float& rstd) {
  float s = 0.f, q = 0.f;
  #pragma unroll
  for (int j = 0; j < 8; ++j) { float v = x[lane + 64 * j]; s += v; q += v * v; }
  #pragma unroll
  for (int off = 32; off; off >>= 1) { s += __shfl_xor(s, off); q += __shfl_xor(q, off); }
  mu = s * (1.f / 512.f);
  float var = q * (1.f / 512.f) - mu * mu;
  rstd = rsqrtf(var + 1e-5f);
}

// gathered LN+ReLU: block i handles token lists[i] (skip if i >= cnt)
__global__ void k_ln_relu_g(float* __restrict__ T, const float* __restrict__ g,
                            const float* __restrict__ b,
                            const int* __restrict__ lists, const int* __restrict__ cnt) {
  int i = blockIdx.x;
  if (i >= *cnt) return;
  int row = lists[i];
  int lane = threadIdx.x;
  float* x = T + (size_t)row * 512;
  float mu, rstd; wave_ln_stats(x, lane, mu, rstd);
  #pragma unroll
  for (int j = 0; j < 8; ++j) {
    int d = lane + 64 * j;
    float v = (x[d] - mu) * rstd * g[d] + b[d];
    x[d] = fmaxf(v, 0.f);
  }
}

__global__ void k_ln_waccum(const float* __restrict__ T, float* __restrict__ H,
                            const float* __restrict__ g, const float* __restrict__ b,
                            const float* __restrict__ WT, int e) {
  int row = blockIdx.x;
  float w = WT[(size_t)row * 4 + e];
  if (w == 0.f) return;
  int lane = threadIdx.x;
  const float* x = T + (size_t)row * 512;
  float mu, rstd; wave_ln_stats(x, lane, mu, rstd);
  float* h = H + (size_t)row * 512;
  #pragma unroll
  for (int j = 0; j < 8; ++j) {
    int d = lane + 64 * j;
    h[d] += w * ((x[d] - mu) * rstd * g[d] + b[d]);
  }
}

__global__ void k_ln_pad(const float* __restrict__ H, float* __restrict__ XLn,
                         const float* __restrict__ g, const float* __restrict__ b) {
  int row = blockIdx.x; int lane = threadIdx.x;
  int bb = row / NPD, i = row % NPD;
  float* y = XLn + (size_t)row * 512;
  if (i < PAD_FRONT) {
    #pragma unroll
    for (int j = 0; j < 8; ++j) y[lane + 64 * j] = 0.f;
    return;
  }
  const float* x = H + ((size_t)bb * NTOK + (i - PAD_FRONT)) * 512;
  float mu, rstd; wave_ln_stats(x, lane, mu, rstd);
  #pragma unroll
  for (int j = 0; j < 8; ++j) {
    int d = lane + 64 * j;
    y[d] = (x[d] - mu) * rstd * g[d] + b[d];
  }
}

__global__ void k_xmean(const float* __restrict__ XLn, float* __restrict__ Xm) {
  int z = blockIdx.x;            // b*256 + jm
  int c = threadIdx.x;           // 512
  int b = z >> 8, jm = z & 255;
  const float* base = XLn + ((size_t)b * NPD + jm * LGRP) * 512 + c;
  float s = 0.f;
  #pragma unroll
  for (int t = 0; t < LGRP; ++t) s += base[(size_t)t * 512];
  Xm[(size_t)z * 512 + c] = s * (1.f / LGRP);
}

__global__ __launch_bounds__(256) void k_attn2(const float* __restrict__ QL,
                                               const float* __restrict__ KL,
                                               float* __restrict__ A2) {
  int z = blockIdx.x; int bh = z >> 8, j = z & 255;
  int b = bh >> 3, h = bh & 7;
  int t = threadIdx.x;
  __shared__ float q[64]; __shared__ float red[256];
  __shared__ float mshare, sshare;
  if (t < 64) q[t] = QL[((size_t)b * 256 + j) * 512 + h * 64 + t];
  __syncthreads();
  const float* kl = KL + ((size_t)b * 256 + t) * 512 + h * 64;
  float s = 0.f;
  #pragma unroll
  for (int d = 0; d < 64; ++d) s += q[d] * kl[d];
  red[t] = s; __syncthreads();
  for (int st = 128; st; st >>= 1) { if (t < st) red[t] = fmaxf(red[t], red[t + st]); __syncthreads(); }
  if (t == 0) mshare = red[0];
  __syncthreads();
  float e = expf(s - mshare);
  red[t] = e; __syncthreads();
  for (int st = 128; st; st >>= 1) { if (t < st) red[t] += red[t + st]; __syncthreads(); }
  if (t == 0) sshare = red[0];
  __syncthreads();
  A2[((size_t)bh * 256 + j) * 256 + t] = e / sshare;
}

__global__ __launch_bounds__(256) void k_pinv_scalars(const float* __restrict__ A2,
                                                      unsigned int* __restrict__ sc) {
  int bh = blockIdx.x; int t = threadIdx.x;
  const float* A = A2 + (size_t)bh * 65536;
  float rowsum = 0.f, colsum = 0.f;
  for (int jj = 0; jj < 256; ++jj) {
    rowsum += fabsf(A[(size_t)t * 256 + jj]);
    colsum += fabsf(A[(size_t)jj * 256 + t]);
  }
  __shared__ float sh[256];
  sh[t] = rowsum; __syncthreads();
  for (int s = 128; s; s >>= 1) { if (t < s) sh[t] = fmaxf(sh[t], sh[t + s]); __syncthreads(); }
  if (t == 0) atomicMax(&sc[0], __float_as_uint(sh[0]));
  __syncthreads();
  sh[t] = colsum; __syncthreads();
  for (int s = 128; s; s >>= 1) { if (t < s) sh[t] = fmaxf(sh[t], sh[t + s]); __syncthreads(); }
  if (t == 0) atomicMax(&sc[1], __float_as_uint(sh[0]));
}

// V [bh][NPD][64] hi/lo -> Vt [bh][64][NPD] hi/lo. grid (NPD/64, NBH)
__global__ __launch_bounds__(256) void k_vtpose(const unsigned short* __restrict__ VrH,
    const unsigned short* __restrict__ VrL,
    unsigned short* __restrict__ VtH, unsigned short* __restrict__ VtL) {
  __shared__ unsigned short TH[64][72], TL[64][72];
  int i0 = blockIdx.x * 64, bh = blockIdx.y;
  int t = threadIdx.x;
  const unsigned short* sH = VrH + ((size_t)bh * NPD + i0) * 64;
  const unsigned short* sL = VrL + ((size_t)bh * NPD + i0) * 64;
  #pragma unroll
  for (int u = 0; u < 2; ++u) {
    int idx = t + 256 * u;
    int r = idx >> 3, c8 = (idx & 7) * 8;
    *(short8v*)&TH[r][c8] = *(const short8v*)&sH[idx * 8];
    *(short8v*)&TL[r][c8] = *(const short8v*)&sL[idx * 8];
  }
  __syncthreads();
  #pragma unroll
  for (int u = 0; u < 2; ++u) {
    int idx = t + 256 * u;
    int d = idx >> 3, c8 = (idx & 7) * 8;
    unsigned short h8[8], l8[8];
    #pragma unroll
    for (int e = 0; e < 8; ++e) { h8[e] = TH[c8 + e][d]; l8[e] = TL[c8 + e][d]; }
    *(short8v*)&VtH[((size_t)bh * 64 + d) * NPD + i0 + c8] = *(short8v*)&h8[0];
    *(short8v*)&VtL[((size_t)bh * 64 + d) * NPD + i0 + c8] = *(short8v*)&l8[0];
  }
}

// KL [b][256][512] fp32 -> KLH/KLL [bh][256][64]. grid 2048 x 256
__global__ void k_cvt_kl(const float* __restrict__ KL, unsigned short* __restrict__ KH,
                         unsigned short* __restrict__ KLo) {
  int idx = blockIdx.x * 256 + threadIdx.x;
  int bh = idx >> 14, j = (idx >> 6) & 255, d = idx & 63;
  int b = bh >> 3, h = bh & 7;
  float v = KL[((size_t)b * 256 + j) * 512 + h * 64 + d];
  unsigned short hi = f2bf(v);
  KH[idx] = hi; KLo[idx] = f2bf(v - bf2f(hi));
}

// W2b [bh][256][64] fp32 -> W2t hi/lo [bh][64][256]. grid 2048 x 256
__global__ void k_cvt_w2t(const float* __restrict__ W2b, unsigned short* __restrict__ WH,
                          unsigned short* __restrict__ WL) {
  int idx = blockIdx.x * 256 + threadIdx.x;
  int bh = idx >> 14, d = (idx >> 8) & 63, j = idx & 255;
  float v = W2b[((size_t)bh * 256 + j) * 64 + d];
  unsigned short hi = f2bf(v);
  WH[idx] = hi; WL[idx] = f2bf(v - bf2f(hi));
}

// ---- MFMA flash attention, pre-split K/V; P hi-only PV ----
__global__ __launch_bounds__(256) void k_flash_pre(
    const float* __restrict__ Qp, long long Qsb, long long Qsh, int Qsr,
    const unsigned short* __restrict__ KHg, const unsigned short* __restrict__ KLg,
    long long Ksbh,
    const unsigned short* __restrict__ VtHg, const unsigned short* __restrict__ VtLg,
    long long Vsbh, int Vrow,
    float* __restrict__ Op, long long Osb, long long Osh, int Osr,
    float* __restrict__ Opart, float* __restrict__ ML,
    int tiles_per_chunk, int mode)
{
  int jt = blockIdx.x, bh = blockIdx.y, ch = blockIdx.z;
  int b = bh >> 3, h = bh & 7;
  const float* Qb = Qp + (size_t)b * Qsb + (size_t)h * Qsh;
  const unsigned short* KbH = KHg + (size_t)bh * Ksbh;
  const unsigned short* KbL = KLg + (size_t)bh * Ksbh;
  const unsigned short* VbH = VtHg + (size_t)bh * Vsbh;
  const unsigned short* VbL = VtLg + (size_t)bh * Vsbh;
  int tid = threadIdx.x;
  int wave = tid >> 6, lane = tid & 63;
  int r16 = lane & 15, g = lane >> 4;
  int q0 = jt * 64 + wave * 16;

  __shared__ unsigned short KsH[64][72], KsL[64][72];   // K; KsH reused as P after QK
  __shared__ unsigned short VtH[64][72], VtL[64][72];   // V transposed [d][key]

  short8v qh[2], ql[2];
  #pragma unroll
  for (int kk = 0; kk < 2; ++kk) {
    const float* qr = Qb + (size_t)(q0 + r16) * Qsr + kk * 32 + g * 8;
    float4 v0 = *(const float4*)qr;
    float4 v1 = *(const float4*)(qr + 4);
    float vs[8] = {v0.x, v0.y, v0.z, v0.w, v1.x, v1.y, v1.z, v1.w};
    unsigned short hh[8], llo[8];
    #pragma unroll
    for (int e = 0; e < 8; ++e) {
      hh[e] = f2bf(vs[e]); llo[e] = f2bf(vs[e] - bf2f(hh[e]));
    }
    qh[kk] = *(short8v*)&hh[0];
    ql[kk] = *(short8v*)&llo[0];
  }

  f32x4 O4[4] = {};
  float m[4], lsum[4];
  #pragma unroll
  for (int j = 0; j < 4; ++j) { m[j] = -1e30f; lsum[j] = 0.f; }

  int t0 = ch * tiles_per_chunk;
  for (int tt = t0; tt < t0 + tiles_per_chunk; ++tt) {
    int key0 = tt * 64;
    __syncthreads();
    {
      const unsigned short* ksrcH = KbH + (size_t)key0 * 64;
      const unsigned short* ksrcL = KbL + (size_t)key0 * 64;
      #pragma unroll
      for (int u = 0; u < 2; ++u) {
        int idx = tid + 256 * u;
        int r = idx >> 3, c8 = (idx & 7) * 8;
        *(short8v*)&KsH[r][c8] = *(const short8v*)&ksrcH[idx * 8];
        *(short8v*)&KsL[r][c8] = *(const short8v*)&ksrcL[idx * 8];
      }
      const unsigned short* vsrcH = VbH + key0;
      const unsigned short* vsrcL = VbL + key0;
      #pragma unroll
      for (int u = 0; u < 2; ++u) {
        int idx = tid + 256 * u;
        int d = idx >> 3, c8 = (idx & 7) * 8;
        *(short8v*)&VtH[d][c8] = *(const short8v*)&vsrcH[(size_t)d * Vrow + c8];
        *(short8v*)&VtL[d][c8] = *(const short8v*)&vsrcL[(size_t)d * Vrow + c8];
      }
    }
    __syncthreads();
    f32x4 S[4] = {};
    #pragma unroll
    for (int kk = 0; kk < 2; ++kk)
      #pragma unroll
      for (int nt = 0; nt < 4; ++nt) {
        short8v kh = *(const short8v*)&KsH[nt * 16 + r16][kk * 32 + g * 8];
        short8v kl = *(const short8v*)&KsL[nt * 16 + r16][kk * 32 + g * 8];
        S[nt] = __builtin_amdgcn_mfma_f32_16x16x32_bf16(qh[kk], kh, S[nt], 0, 0, 0);
        S[nt] = __builtin_amdgcn_mfma_f32_16x16x32_bf16(qh[kk], kl, S[nt], 0, 0, 0);
        S[nt] = __builtin_amdgcn_mfma_f32_16x16x32_bf16(ql[kk], kh, S[nt], 0, 0, 0);
      }
    float tmax[4];
    #pragma unroll
    for (int j = 0; j < 4; ++j)
      tmax[j] = fmaxf(fmaxf(S[0][j], S[1][j]), fmaxf(S[2][j], S[3][j]));
    #pragma unroll
    for (int off = 8; off; off >>= 1)
      #pragma unroll
      for (int j = 0; j < 4; ++j) tmax[j] = fmaxf(tmax[j], __shfl_xor(tmax[j], off));
    float corr[4];
    #pragma unroll
    for (int j = 0; j < 4; ++j) {
      float mn = fmaxf(m[j], tmax[j]);
      corr[j] = expf(m[j] - mn);
      m[j] = mn;
    }
    __syncthreads();
    float tl[4] = {0.f, 0.f, 0.f, 0.f};
    #pragma unroll
    for (int nt = 0; nt < 4; ++nt)
      #pragma unroll
      for (int j = 0; j < 4; ++j) {
        float p = expf(S[nt][j] - m[j]);
        tl[j] += p;
        KsH[wave * 16 + g * 4 + j][nt * 16 + r16] = f2bf(p);   // P hi only
      }
    #pragma unroll
    for (int off = 8; off; off >>= 1)
      #pragma unroll
      for (int j = 0; j < 4; ++j) tl[j] += __shfl_xor(tl[j], off);
    #pragma unroll
    for (int j = 0; j < 4; ++j) lsum[j] = lsum[j] * corr[j] + tl[j];
    #pragma unroll
    for (int nt = 0; nt < 4; ++nt)
      #pragma unroll
      for (int j = 0; j < 4; ++j) O4[nt][j] *= corr[j];
    #pragma unroll
    for (int kk = 0; kk < 2; ++kk) {
      short8v ph = *(const short8v*)&KsH[wave * 16 + r16][kk * 32 + g * 8];
      #pragma unroll
      for (int nt = 0; nt < 4; ++nt) {
        short8v vh = *(const short8v*)&VtH[nt * 16 + r16][kk * 32 + g * 8];
        short8v vl = *(const short8v*)&VtL[nt * 16 + r16][kk * 32 + g * 8];
        O4[nt] = __builtin_amdgcn_mfma_f32_16x16x32_bf16(ph, vh, O4[nt], 0, 0, 0);
        O4[nt] = __builtin_amdgcn_mfma_f32_16x16x32_bf16(ph, vl, O4[nt], 0, 0, 0);
      }
    }
  }
  if (mode == 0) {
    float* Ob = Op + (size_t)b * Osb + (size_t)h * Osh;
    float inv[4];
    #pragma unroll
    for (int j = 0; j < 4; ++j) inv[j] = 1.f / lsum[j];
    #pragma unroll
    for (int nt = 0; nt < 4; ++nt)
      #pragma unroll
      for (int j = 0; j < 4; ++j)
        Ob[(size_t)(q0 + g * 4 + j) * Osr + nt * 16 + r16] = O4[nt][j] * inv[j];
  } else {
    #pragma unroll
    for (int j = 0; j < 4; ++j) {
      size_t rowbase = ((size_t)ch * NBH + bh) * 256 + q0 + g * 4 + j;
      #pragma unroll
      for (int nt = 0; nt < 4; ++nt)
        Opart[rowbase * 64 + nt * 16 + r16] = O4[nt][j];
      if (r16 == 0) { ML[rowbase * 2] = m[j]; ML[rowbase * 2 + 1] = lsum[j]; }
    }
  }
}

// combine NCH chunks -> A3V[bh,256,64]. grid (16, NBH), 256 thr.
__global__ __launch_bounds__(256) void k_flash_comb(const float* __restrict__ Opart,
                                                    const float* __restrict__ ML,
                                                    float* __restrict__ A3V) {
  int jt = blockIdx.x, bh = blockIdx.y;
  int t = threadIdx.x;
  int jr = t >> 4, q16 = t & 15;
  int row = jt * 16 + jr;
  float mv[NCH], lv[NCH];
  float M = -1e30f;
  #pragma unroll
  for (int ch = 0; ch < NCH; ++ch) {
    size_t base = (((size_t)ch * NBH + bh) * 256 + row);
    mv[ch] = ML[base * 2]; lv[ch] = ML[base * 2 + 1];
    M = fmaxf(M, mv[ch]);
  }
  float L = 0.f;
  float4 O = make_float4(0.f, 0.f, 0.f, 0.f);
  #pragma unroll
  for (int ch = 0; ch < NCH; ++ch) {
    float c = expf(mv[ch] - M);
    L += c * lv[ch];
    size_t base = (((size_t)ch * NBH + bh) * 256 + row);
    float4 o = *(const float4*)&Opart[base * 64 + q16 * 4];
    O.x += c * o.x; O.y += c * o.y; O.z += c * o.z; O.w += c * o.w;
  }
  float inv = 1.f / L;
  *(float4*)&A3V[((size_t)bh * 256 + row) * 64 + q16 * 4] =
      make_float4(O.x * inv, O.y * inv, O.z * inv, O.w * inv);
}

// conv over i from Vt hi/lo; grid (NPD/128, NBH), 256 thr.
__global__ __launch_bounds__(256) void k_conv_add(const unsigned short* __restrict__ VtHg,
    const unsigned short* __restrict__ VtLg, const float* __restrict__ cw,
    float* __restrict__ out) {
  int it = blockIdx.x, bh = blockIdx.y;
  int b = bh >> 3, h = bh & 7;
  int i0 = it * 128;
  int t = threadIdx.x;
  __shared__ float Vs[64][161];
  const unsigned short* vh = VtHg + (size_t)bh * 64 * NPD;
  const unsigned short* vl = VtLg + (size_t)bh * 64 * NPD;
  for (int u = 0; u < 40; ++u) {
    int idx = t + 256 * u;
    int d = idx / 160, ii = idx - d * 160;
    int gi = i0 - 16 + ii;
    float v = 0.f;
    if (gi >= 0 && gi < NPD) {
      size_t a = (size_t)d * NPD + gi;
      v = bf2f(vh[a]) + bf2f(vl[a]);
    }
    Vs[d][ii] = v;
  }
  __syncthreads();
  float w[CONVK];
  #pragma unroll
  for (int p = 0; p < CONVK; ++p) w[p] = cw[h * CONVK + p];
  int rgrp = t >> 6, d = t & 63;
  for (int r = rgrp * 32; r < rgrp * 32 + 32; ++r) {
    float acc = 0.f;
    #pragma unroll
    for (int p = 0; p < CONVK; ++p) acc += w[p] * Vs[d][r + p];
    out[((size_t)b * NPD + i0 + r) * 512 + h * 64 + d] += acc;
  }
}

__global__ void k_out_write(const float* __restrict__ H, float* __restrict__ out) {
  size_t n0 = (size_t)BATCH * 512;
  size_t total = n0 + (size_t)BATCH * (NTOK - 1) * 512;
  for (size_t idx = (size_t)blockIdx.x * blockDim.x + threadIdx.x; idx < total;
       idx += (size_t)gridDim.x * blockDim.x) {
    float v;
    if (idx < n0) {
      int b = (int)(idx >> 9); int d = (int)(idx & 511);
      v = H[((size_t)b * NTOK) * 512 + d];
    } else {
      size_t r = idx - n0;
      size_t bj = r >> 9; int d = (int)(r & 511);
      int b = (int)(bj / (NTOK - 1)); int j = (int)(bj % (NTOK - 1));
      v = H[((size_t)b * NTOK + 1 + j) * 512 + d];
    }
    out[idx] = v;
  }
}

// ============================ host ============================

extern "C" void kernel_launch(void* const* d_in, const int* in_sizes, int n_in,
                              void* d_out, int out_size, void* d_ws, size_t ws_size,
                              hipStream_t stream) {
  (void)in_sizes; (void)n_in;

  const float* feat = (const float*)d_in[0];
  const float* cls  = (const float*)d_in[1];
  const float* m1_gw = (const float*)d_in[2];  const float* m1_gb = (const float*)d_in[3];
  const float* m1_f1w = (const float*)d_in[4]; const float* m1_f1b = (const float*)d_in[5];
  const float* m1_l1g = (const float*)d_in[6]; const float* m1_l1b = (const float*)d_in[7];
  const float* m1_f2w = (const float*)d_in[8]; const float* m1_f2b = (const float*)d_in[9];
  const float* m1_l2g = (const float*)d_in[10]; const float* m1_l2b = (const float*)d_in[11];
  const float* m2_gw = (const float*)d_in[12]; const float* m2_gb = (const float*)d_in[13];
  const float* m2_f1w = (const float*)d_in[14]; const float* m2_f1b = (const float*)d_in[15];
  const float* m2_l1g = (const float*)d_in[16]; const float* m2_l1b = (const float*)d_in[17];
  const float* m2_f2w = (const float*)d_in[18]; const float* m2_f2b = (const float*)d_in[19];
  const float* m2_l2g = (const float*)d_in[20]; const float* m2_l2b = (const float*)d_in[21];
  const float* l1_ng = (const float*)d_in[22]; const float* l1_nb = (const float*)d_in[23];
  const float* l1_qkvw = (const float*)d_in[24]; const float* l1_outw = (const float*)d_in[25];
  const float* l1_outb = (const float*)d_in[26]; const float* l1_convw = (const float*)d_in[27];
  const float* l2_ng = (const float*)d_in[28]; const float* l2_nb = (const float*)d_in[29];
  const float* l2_qkvw = (const float*)d_in[30]; const float* l2_outw = (const float*)d_in[31];
  const float* l2_outb = (const float*)d_in[32]; const float* l2_convw = (const float*)d_in[33];

  // ---- workspace layout (units: fp32 elements) ----
  constexpr size_t SZ_H    = (size_t)BN_TOK * 512;
  constexpr size_t SZ_ROW  = (size_t)RPAD * 512;
  float* W = (float*)d_ws;
  float* H  = W;
  float* WT = W + SZ_H;
  unsigned int* SC = (unsigned int*)(W + SZ_H + 97360);
  float* pool = W + SZ_H + 97360 + 16;

  float* R2 = pool;                    // XLn -> AttnO ; MoE T1
  float* R3 = pool + SZ_ROW;           // Vr hi/lo -> K hi/lo -> Qb ; MoE T2
  float* R4 = pool + 2 * SZ_ROW;       // Vt hi/lo ; MoE Xsnap
  float* SMALL = pool + 3 * SZ_ROW;
  float* Xm  = SMALL;                  // 524288; later ML for flash3
  float* QL  = SMALL + 524288;
  float* KL  = SMALL + 1048576;        // contiguous after QL (omode-7 split write)
  float* A2  = SMALL + 1572864;        // 2.1M; MoE: per-expert Bt; post-pinv: KLH/...
  float* Zb  = SMALL + 3670016;        // MoE: LISTS; pinv Y; post-pinv: Opart
  float* XZp = SMALL + 5767168;        // pinv F1
  float* Wa  = SMALL + 7864320;        // pinv F2; post-pinv: qkv/out weight Bt
  float* Wb  = SMALL + 9961472;        // pinv Z (z_final)
  float* A3V = SMALL + 12058624;
  float* W2b = SMALL + 12582912;
  size_t total_f = (SZ_H + 97360 + 16) + 3 * SZ_ROW + 13107200;
  if (total_f * 4 > ws_size) {
    k_diag_fill<<<2048, 256, 0, stream>>>((float*)d_out, (size_t)out_size,
                                          (float)(ws_size >> 20));
    return;
  }

  k_build_h<<<2048, 256, 0, stream>>>(feat, cls, H);

  auto run_moe = [&](const float* gw, const float* gb, const float* f1w, const float* f1b,
                     const float* l1g, const float* l1b, const float* f2w, const float* f2b,
                     const float* l2g, const float* l2b, int E, int k) {
    float* T1 = R2; float* T2 = R3; float* Xsnap = R4;
    // per-expert Bt slabs: fc1 at A2, fc2 at A2 + 1,048,576 floats (E*262144 ushorts each)
    unsigned short* BtF1H = (unsigned short*)A2;
    unsigned short* BtF1L = BtF1H + (size_t)E * 262144;
    unsigned short* BtF2H = (unsigned short*)(A2 + 1048576);
    unsigned short* BtF2L = BtF2H + (size_t)E * 262144;
    int* LISTS = (int*)Zb;                       // E x LISTCAP ints (pinv region, dead)
    int* CNT = (int*)(SC + 4);                   // 4 ints
    hipMemcpyAsync(Xsnap, H, SZ_H * 4, hipMemcpyDeviceToDevice, stream);
    hipMemsetAsync(CNT, 0, 4 * sizeof(int), stream);
    k_gate<<<BN_TOK, 64, 0, stream>>>(H, gw, gb, WT, E, k);
    k_lists<<<(BN_TOK + 63) / 64, 64, 0, stream>>>(WT, CNT, LISTS, E);
    k_wconv<<<dim3(8, 8, E), 256, 0, stream>>>(f1w, 512, 262144LL, BtF1H, BtF1L, 262144LL);
    k_wconv<<<dim3(8, 8, E), 256, 0, stream>>>(f2w, 512, 262144LL, BtF2H, BtF2L, 262144LL);
    dim3 g(4, (BN_TOK + 127) / 128, 1);
    for (int e = 0; e < E; ++e) {
      const int* lst = LISTS + (size_t)e * LISTCAP;
      const int* cnt = CNT + e;
      k_gemm_mfma<<<g, 256, 0, stream>>>(Xsnap, BtF1H + (size_t)e * 262144,
          BtF1L + (size_t)e * 262144, f1b + e * 512, T1,
          BN_TOK, 512, 512, 1.f, 0, nullptr, lst, cnt);
      k_ln_relu_g<<<BN_TOK, 64, 0, stream>>>(T1, l1g + e * 512, l1b + e * 512, lst, cnt);
      k_gemm_mfma<<<g, 256, 0, stream>>>(T1, BtF2H + (size_t)e * 262144,
          BtF2L + (size_t)e * 262144, f2b + e * 512, T2,
          BN_TOK, 512, 512, 1.f, 0, nullptr, lst, cnt);
      k_ln_waccum<<<BN_TOK, 64, 0, stream>>>(T2, H, l2g + e * 512, l2b + e * 512, WT, e);
    }
  };

  auto run_attn = [&](const float* ng, const float* nb, const float* qkvw, const float* outw,
                      const float* outb, const float* convw) {
    float* XLn = R2; float* AttnO = R2;
    float* Qb = R3;
    unsigned short* VrH = (unsigned short*)R3;
    unsigned short* VrL = VrH + 12582912;
    unsigned short* KH  = (unsigned short*)R3;
    unsigned short* KLo = KH + 12582912;
    unsigned short* VtH = (unsigned short*)R4;
    unsigned short* VtL = VtH + 12582912;
    k_ln_pad<<<RPAD, 64, 0, stream>>>(H, XLn, ng, nb);
    k_xmean<<<BATCH * 256, 512, 0, stream>>>(XLn, Xm);
    // merged QL|KL projection (omode 7: alpha 0.125 for Q half, 1.0 for K half)
    k_gemm<<<dim3(16, 16, 1), 256, 0, stream>>>(Xm, qkvw, nullptr, QL,
        1024, 1024, 512, 512, 1536, 512, 0, 0, 0, 1.f, 7, 0.f);
    k_attn2<<<NBH * 256, 256, 0, stream>>>(QL, KL, A2);
    hipMemsetAsync(SC, 0, 8, stream);
    k_pinv_scalars<<<NBH, 256, 0, stream>>>(A2, SC);
    // ---- pinv Newton-Schulz: 4 fused dispatches/iter (transpose in epilogue) ----
    k_yz0<<<2048, 256, 0, stream>>>(A2, Zb, Wb, SC);   // Y = z^T, Z = z
    float* Y = Zb; float* Z = Wb; float* F1 = XZp; float* F2 = Wa;
    dim3 gq(2, 2, NBH);
    for (int it = 0; it < 6; ++it) {
      int np = (it < 4) ? 1 : 3;
      k_gemm_mfma2<<<gq, 256, 0, stream>>>(A2, Y, F1, 1.f, 0, 0.f, 0, np, F2);   // F1=XZ, F2=XZT
      k_gemm_mfma2<<<gq, 256, 0, stream>>>(F2, F1, Y, 1.f, 5, 15.f, 1, np, nullptr); // Y=QT
      k_gemm_mfma2<<<gq, 256, 0, stream>>>(Y, F1, F2, 1.f, 5, 13.f, 0, np, nullptr); // F2=PT
      k_gemm_mfma2<<<gq, 256, 0, stream>>>(Z, F2, F1, 0.25f, 0, 0.f, 0, np, Y);  // F1=z_new, Y=z_new^T
      float* tz = Z; Z = F1; F1 = tz;
    }
    // z_final in Z (Y holds z_final^T, unused). A2 region reusable now.
    unsigned short* KLH = (unsigned short*)A2;
    unsigned short* KLL = KLH + 524288;
    unsigned short* W2tH = KLH + 1048576;
    unsigned short* W2tL = KLH + 1572864;
    k_cvt_kl<<<2048, 256, 0, stream>>>(KL, KLH, KLL);
    unsigned short* BtQH = (unsigned short*)Wa;
    unsigned short* BtQL = BtQH + 786432;
    k_wconv<<<dim3(24, 8, 1), 256, 0, stream>>>(qkvw, 1536, 0LL, BtQH, BtQL, 0LL);
    dim3 gr(4, (RPAD + 127) / 128, 1);
    // V projection -> hi/lo packed per-head in R3; transpose -> R4
    k_gemm_mfma<<<gr, 256, 0, stream>>>(XLn, BtQH + 1024 * 512, BtQL + 1024 * 512, nullptr,
        (float*)VrH, RPAD, 512, 512, 1.f, 6, VrL, nullptr, nullptr);
    k_vtpose<<<dim3(NPD / 64, NBH), 256, 0, stream>>>(VrH, VrL, VtH, VtL);
    // K projection -> hi/lo packed in R3 (Vr dead)
    k_gemm_mfma<<<gr, 256, 0, stream>>>(XLn, BtQH + 512 * 512, BtQL + 512 * 512, nullptr,
        (float*)KH, RPAD, 512, 512, 1.f, 6, KLo, nullptr, nullptr);
    // attn3: split-kv flash; Opart in Zb..XZp (4.19M), ML in Xm
    k_flash_pre<<<dim3(4, NBH, NCH), 256, 0, stream>>>(
        QL, 131072LL, 64LL, 512,
        KH, KLo, (long long)NPD * 64,
        VtH, VtL, (long long)64 * NPD, NPD,
        nullptr, 0, 0, 0, Zb, Xm, NPD / (64 * NCH), 1);
    k_flash_comb<<<dim3(16, NBH), 256, 0, stream>>>(Zb, Xm, A3V);
    // W2b[bh] = z_final @ A3V
    k_gemm<<<dim3(1, 4, NBH), 256, 0, stream>>>(Z, A3V, nullptr, W2b,
        256, 64, 256, 256, 64, 64, 65536, 16384, 16384, 1.f, 0, 0.f);
    k_cvt_w2t<<<2048, 256, 0, stream>>>(W2b, W2tH, W2tL);
    // Q projection (scaled) -> fp32 R3 (K dead after flash3)
    k_gemm_mfma<<<gr, 256, 0, stream>>>(XLn, BtQH, BtQL, nullptr,
        Qb, RPAD, 512, 512, 0.125f, 0, nullptr, nullptr, nullptr);
    // attn1 flash -> AttnO (over XLn, dead after Q proj)
    k_flash_pre<<<dim3(NPD / 64, NBH, 1), 256, 0, stream>>>(
        Qb, (long long)NPD * 512, 64LL, 512,
        KLH, KLL, 16384LL,
        W2tH, W2tL, 16384LL, 256,
        AttnO, (long long)NPD * 512, 64LL, 512,
        nullptr, nullptr, 4, 0);
    k_conv_add<<<dim3(NPD / 128, NBH), 256, 0, stream>>>(VtH, VtL, convw, AttnO);
    // out-proj, cropped + accumulated into H (Bt in Wa, dead)
    unsigned short* BtOH = (unsigned short*)Wa;
    unsigned short* BtOL = BtOH + 262144;
    k_wconv<<<dim3(8, 8, 1), 256, 0, stream>>>(outw, 512, 0LL, BtOH, BtOL, 0LL);
    k_gemm_mfma<<<gr, 256, 0, stream>>>(AttnO, BtOH, BtOL, outb,
        H, RPAD, 512, 512, 1.f, 2, nullptr, nullptr, nullptr);
  };

  run_moe(m1_gw, m1_gb, m1_f1w, m1_f1b, m1_l1g, m1_l1b, m1_f2w, m1_f2b, m1_l2g, m1_l2b, 2, 1);
  run_attn(l1_ng, l1_nb, l1_qkvw, l1_outw, l1_outb, l1_convw);
  run_moe(m2_gw, m2_gb, m2_f1w, m2_f1b, m2_l1g, m2_l1b, m2_f2w, m2_f2b, m2_l2g, m2_l2b, 4, 2);
  run_attn(l2_ng, l2_nb, l2_qkvw, l2_outw, l2_outb, l2_convw);

  k_out_write<<<2048, 256, 0, stream>>>(H, (float*)d_out);
}

// Round 18
// 3607.359 us; speedup vs baseline: 1.0466x; 1.0011x over previous
//
#include <hip/hip_runtime.h>
#include <hip/hip_bf16.h>

// ---- problem constants ----
constexpr int BATCH = 4;
constexpr int NTOK  = 6085;            // 1 cls + 6084 (wrap-padded to 78^2)
constexpr int BN_TOK = BATCH * NTOK;   // 24340
constexpr int NPD   = 6144;            // 6085 front-padded to multiple of 256
constexpr int RPAD  = BATCH * NPD;     // 24576
constexpr int DMODEL = 512;
constexpr int NH = 8, DH = 64;
constexpr int NBH = BATCH * NH;        // 32
constexpr int LGRP = NPD / 256;        // 24 tokens per landmark
constexpr int PAD_FRONT = 59;
constexpr int CONVK = 33;
constexpr int NCH = 8;                 // attn3 kv chunks
constexpr int LISTCAP = 24576;         // per-expert token list capacity

typedef __attribute__((ext_vector_type(8))) short short8v;
typedef __attribute__((ext_vector_type(4))) float f32x4;

__device__ __forceinline__ unsigned short f2bf(float f) {
  unsigned u = __float_as_uint(f);
  u += 0x7FFF + ((u >> 16) & 1);
  return (unsigned short)(u >> 16);
}
__device__ __forceinline__ float bf2f(unsigned short h) {
  return __uint_as_float((unsigned)h << 16);
}

// ============================ kernels ============================

__global__ void k_build_h(const float* __restrict__ feat, const float* __restrict__ cls,
                          float* __restrict__ H) {
  size_t total = (size_t)BN_TOK * DMODEL;
  for (size_t idx = (size_t)blockIdx.x * blockDim.x + threadIdx.x; idx < total;
       idx += (size_t)gridDim.x * blockDim.x) {
    int d = (int)(idx & 511);
    size_t tok = idx >> 9;
    int b = (int)(tok / NTOK), n = (int)(tok % NTOK);
    float v;
    if (n == 0) v = cls[d];
    else {
      int i = n - 1; if (i >= 6000) i -= 6000;
      v = feat[((size_t)b * 6000 + i) * DMODEL + d];
    }
    H[idx] = v;
  }
}

__global__ void k_diag_fill(float* __restrict__ out, size_t n, float val) {
  for (size_t i = (size_t)blockIdx.x * blockDim.x + threadIdx.x; i < n;
       i += (size_t)gridDim.x * blockDim.x)
    out[i] = val;
}

// weight convert: W fp32 [512][ldb] (use N cols) -> hi/lo bf16 [N][512] (transposed)
// batched over blockIdx.z (expert): W += z*wstride, hi/lo += z*hstride
__global__ __launch_bounds__(256) void k_wconv(const float* __restrict__ W, int ldb,
    long long wstride, unsigned short* __restrict__ hi, unsigned short* __restrict__ lo,
    long long hstride) {
  __shared__ unsigned short Th[64][80], Tl[64][80];
  int z = blockIdx.z;
  W  += (size_t)z * (size_t)wstride;
  hi += (size_t)z * (size_t)hstride;
  lo += (size_t)z * (size_t)hstride;
  int bk = blockIdx.y * 64, bn = blockIdx.x * 64;
  int t = threadIdx.x;
  int kr = t >> 2, cq = (t & 3) * 16;
  const float* src = W + (size_t)(bk + kr) * ldb + bn + cq;
  #pragma unroll
  for (int q = 0; q < 4; ++q) {
    float4 v = *(const float4*)(src + q * 4);
    float vs[4] = {v.x, v.y, v.z, v.w};
    #pragma unroll
    for (int e = 0; e < 4; ++e) {
      int n = cq + q * 4 + e;
      unsigned short h = f2bf(vs[e]);
      Th[n][kr] = h;
      Tl[n][kr] = f2bf(vs[e] - bf2f(h));
    }
  }
  __syncthreads();
  int nr = t >> 2, kq = (t & 3) * 16;
  size_t o = (size_t)(bn + nr) * 512 + bk + kq;
  *(short8v*)&hi[o]     = *(const short8v*)&Th[nr][kq];
  *(short8v*)&hi[o + 8] = *(const short8v*)&Th[nr][kq + 8];
  *(short8v*)&lo[o]     = *(const short8v*)&Tl[nr][kq];
  *(short8v*)&lo[o + 8] = *(const short8v*)&Tl[nr][kq + 8];
}

// per-expert token list build: wave ballot compaction, grouped atomic base.
__global__ void k_lists(const float* __restrict__ WT, int* __restrict__ cnt,
                        int* __restrict__ lists, int E) {
  int lane = threadIdx.x;
  int tok = blockIdx.x * 64 + lane;
  for (int e = 0; e < E; ++e) {
    bool sel = (tok < BN_TOK) && (WT[(size_t)tok * 4 + e] != 0.f);
    unsigned long long mask = __ballot(sel);
    int rank = __popcll(mask & ((1ull << lane) - 1ull));
    int n = __popcll(mask);
    int base = 0;
    if (lane == 0 && n > 0) base = atomicAdd(&cnt[e], n);
    base = __shfl(base, 0);
    if (sel) lists[(size_t)e * LISTCAP + base + rank] = tok;
  }
}

// ---- bf16x3 MFMA GEMM: C = alpha*(A@B)+bias. A fp32 [M][lda] (in-kernel split),
// Bt hi/lo bf16 [N][512]. In-loop loads + XCD-chunked block swizzle.
// Optional row gather/scatter: rowidx/cnt (per-expert MoE token lists).
// omode 0: fp32 C; 2: resid-accum crop pad; 6: head-split hi/lo (C/Clo);
// omode 8: fused K|V: gc<512 -> K packed rows (C/Clo); gc>=512 -> V transposed (VtH2/VtL2)
__global__ __launch_bounds__(256) void k_gemm_mfma(const float* __restrict__ A,
    const unsigned short* __restrict__ BtH, const unsigned short* __restrict__ BtL,
    const float* __restrict__ bias, float* __restrict__ C,
    int M, int lda, int ldc, float alpha, int omode, unsigned short* __restrict__ Clo,
    const int* __restrict__ rowidx, const int* __restrict__ cnt,
    unsigned short* __restrict__ VtH2, unsigned short* __restrict__ VtL2)
{
  __shared__ unsigned short AsH[128][40], AsL[128][40];
  __shared__ unsigned short BsH[128][40], BsL[128][40];
  // XCD-chunked bijective block swizzle (m204 form)
  int nwg = gridDim.x * gridDim.y;
  int wid = blockIdx.y * gridDim.x + blockIdx.x;
  int qq = nwg >> 3, rr = nwg & 7;
  int xcd = wid & 7, pos = wid >> 3;
  int Lid = (xcd < rr ? xcd * (qq + 1) : rr * (qq + 1) + (xcd - rr) * qq) + pos;
  int bn = (Lid % gridDim.x) * 128;
  int bm = (Lid / gridDim.x) * 128;
  int Mv = M;
  if (cnt) { Mv = *cnt; if (Mv > M) Mv = M; }
  if (bm >= Mv) return;
  int tid = threadIdx.x;
  int wave = tid >> 6, lane = tid & 63;
  int mo = (wave >> 1) * 64, no = (wave & 1) * 64;
  int r16 = lane & 15, g = lane >> 4;
  f32x4 acc[4][4] = {};
  int srow = tid >> 1, shalf = (tid & 1) * 16;
  int lrow = bm + srow;
  bool avalid = lrow < Mv;
  int arow = lrow;
  if (rowidx && avalid) arow = rowidx[lrow];
  if (!avalid) arow = 0;
  const float* aptr = A + (size_t)arow * lda + shalf;
  const unsigned short* bhptr = BtH + (size_t)(bn + srow) * 512 + shalf;
  const unsigned short* blptr = BtL + (size_t)(bn + srow) * 512 + shalf;
  for (int k0 = 0; k0 < 512; k0 += 32) {
    unsigned short h8[16], l8[16];
    #pragma unroll
    for (int q = 0; q < 4; ++q) {
      float4 v = avalid ? *(const float4*)(aptr + k0 + q * 4) : make_float4(0.f, 0.f, 0.f, 0.f);
      float vs[4] = {v.x, v.y, v.z, v.w};
      #pragma unroll
      for (int e = 0; e < 4; ++e) {
        unsigned short hh = f2bf(vs[e]);
        h8[q * 4 + e] = hh;
        l8[q * 4 + e] = f2bf(vs[e] - bf2f(hh));
      }
    }
    *(short8v*)&AsH[srow][shalf]     = *(short8v*)&h8[0];
    *(short8v*)&AsH[srow][shalf + 8] = *(short8v*)&h8[8];
    *(short8v*)&AsL[srow][shalf]     = *(short8v*)&l8[0];
    *(short8v*)&AsL[srow][shalf + 8] = *(short8v*)&l8[8];
    *(short8v*)&BsH[srow][shalf]     = *(const short8v*)(bhptr + k0);
    *(short8v*)&BsH[srow][shalf + 8] = *(const short8v*)(bhptr + k0 + 8);
    *(short8v*)&BsL[srow][shalf]     = *(const short8v*)(blptr + k0);
    *(short8v*)&BsL[srow][shalf + 8] = *(const short8v*)(blptr + k0 + 8);
    __syncthreads();
    short8v ah[4], al[4], bh[4], bl[4];
    #pragma unroll
    for (int mt = 0; mt < 4; ++mt) {
      ah[mt] = *(const short8v*)&AsH[mo + mt * 16 + r16][g * 8];
      al[mt] = *(const short8v*)&AsL[mo + mt * 16 + r16][g * 8];
    }
    #pragma unroll
    for (int nt = 0; nt < 4; ++nt) {
      bh[nt] = *(const short8v*)&BsH[no + nt * 16 + r16][g * 8];
      bl[nt] = *(const short8v*)&BsL[no + nt * 16 + r16][g * 8];
    }
    #pragma unroll
    for (int mt = 0; mt < 4; ++mt)
      #pragma unroll
      for (int nt = 0; nt < 4; ++nt) {
        acc[mt][nt] = __builtin_amdgcn_mfma_f32_16x16x32_bf16(ah[mt], bh[nt], acc[mt][nt], 0, 0, 0);
        acc[mt][nt] = __builtin_amdgcn_mfma_f32_16x16x32_bf16(ah[mt], bl[nt], acc[mt][nt], 0, 0, 0);
        acc[mt][nt] = __builtin_amdgcn_mfma_f32_16x16x32_bf16(al[mt], bh[nt], acc[mt][nt], 0, 0, 0);
      }
    __syncthreads();
  }
  #pragma unroll
  for (int mt = 0; mt < 4; ++mt)
    #pragma unroll
    for (int nt = 0; nt < 4; ++nt)
      #pragma unroll
      for (int j = 0; j < 4; ++j) {
        int lr = bm + mo + mt * 16 + g * 4 + j;
        int gc = bn + no + nt * 16 + r16;
        if (lr >= Mv) continue;
        int gr = rowidx ? rowidx[lr] : lr;
        float v = alpha * acc[mt][nt][j] + (bias ? bias[gc] : 0.f);
        if (omode == 0) {
          C[(size_t)gr * ldc + gc] = v;
        } else if (omode == 2) {
          int bb = gr / NPD, ii = gr % NPD;
          if (ii >= PAD_FRONT)
            C[((size_t)bb * NTOK + ii - PAD_FRONT) * 512 + gc] += v;
        } else if (omode == 6) {
          int bb = gr / NPD, ii = gr % NPD;
          int hh = gc >> 6, dd = gc & 63;
          size_t idx = (((size_t)bb * NH + hh) * NPD + ii) * 64 + dd;
          unsigned short hi = f2bf(v);
          ((unsigned short*)C)[idx] = hi;
          Clo[idx] = f2bf(v - bf2f(hi));
        } else {  // omode 8: fused K | V-transposed
          int bb = gr / NPD, ii = gr % NPD;
          unsigned short hi = f2bf(v);
          unsigned short lo = f2bf(v - bf2f(hi));
          if (gc < 512) {
            int hh = gc >> 6, dd = gc & 63;
            size_t idx = (((size_t)bb * NH + hh) * NPD + ii) * 64 + dd;
            ((unsigned short*)C)[idx] = hi;
            Clo[idx] = lo;
          } else {
            int gc2 = gc - 512;
            int hh = gc2 >> 6, dd = gc2 & 63;
            size_t idx = (((size_t)bb * NH + hh) * 64 + dd) * (size_t)NPD + ii;
            VtH2[idx] = hi;
            VtL2[idx] = lo;
          }
        }
      }
}

// ---- bf16 MFMA GEMM, both fp32, batched 256x256x256 (pinv). nprod=1 or 3 ----
// Ct (optional): also write transposed result (fused k_tpose).
__global__ __launch_bounds__(256) void k_gemm_mfma2(const float* __restrict__ A,
    const float* __restrict__ Bt, float* __restrict__ C,
    float alpha, int omode, float cdiag, int premap, int nprod, float* __restrict__ Ct)
{
  __shared__ unsigned short AsH[128][40], AsL[128][40];
  __shared__ unsigned short BsH[128][40], BsL[128][40];
  size_t zo = (size_t)blockIdx.z * 65536;
  int bm = blockIdx.y * 128, bn = blockIdx.x * 128;
  int tid = threadIdx.x;
  int wave = tid >> 6, lane = tid & 63;
  int mo = (wave >> 1) * 64, no = (wave & 1) * 64;
  int r16 = lane & 15, g = lane >> 4;
  f32x4 acc[4][4] = {};
  int srow = tid >> 1, shalf = (tid & 1) * 16;
  int grow = bm + srow;
  int gn = bn + srow;
  for (int k0 = 0; k0 < 256; k0 += 32) {
    unsigned short h8[16], l8[16];
    #pragma unroll
    for (int q = 0; q < 4; ++q) {
      float4 v = *(const float4*)&A[zo + (size_t)grow * 256 + k0 + shalf + q * 4];
      float vs[4] = {v.x, v.y, v.z, v.w};
      #pragma unroll
      for (int e = 0; e < 4; ++e) {
        float a = vs[e];
        if (premap) a = ((grow == (k0 + shalf + q * 4 + e)) ? 7.f : 0.f) - a;
        unsigned short hh = f2bf(a);
        h8[q * 4 + e] = hh;
        l8[q * 4 + e] = (nprod == 3) ? f2bf(a - bf2f(hh)) : (unsigned short)0;
      }
    }
    *(short8v*)&AsH[srow][shalf]     = *(short8v*)&h8[0];
    *(short8v*)&AsH[srow][shalf + 8] = *(short8v*)&h8[8];
    *(short8v*)&AsL[srow][shalf]     = *(short8v*)&l8[0];
    *(short8v*)&AsL[srow][shalf + 8] = *(short8v*)&l8[8];
    #pragma unroll
    for (int q = 0; q < 4; ++q) {
      float4 v = *(const float4*)&Bt[zo + (size_t)gn * 256 + k0 + shalf + q * 4];
      float vs[4] = {v.x, v.y, v.z, v.w};
      #pragma unroll
      for (int e = 0; e < 4; ++e) {
        unsigned short hh = f2bf(vs[e]);
        h8[q * 4 + e] = hh;
        l8[q * 4 + e] = (nprod == 3) ? f2bf(vs[e] - bf2f(hh)) : (unsigned short)0;
      }
    }
    *(short8v*)&BsH[srow][shalf]     = *(short8v*)&h8[0];
    *(short8v*)&BsH[srow][shalf + 8] = *(short8v*)&h8[8];
    *(short8v*)&BsL[srow][shalf]     = *(short8v*)&l8[0];
    *(short8v*)&BsL[srow][shalf + 8] = *(short8v*)&l8[8];
    __syncthreads();
    short8v ah[4], al[4], bh[4], bl[4];
    #pragma unroll
    for (int mt = 0; mt < 4; ++mt) {
      ah[mt] = *(const short8v*)&AsH[mo + mt * 16 + r16][g * 8];
      al[mt] = *(const short8v*)&AsL[mo + mt * 16 + r16][g * 8];
    }
    #pragma unroll
    for (int nt = 0; nt < 4; ++nt) {
      bh[nt] = *(const short8v*)&BsH[no + nt * 16 + r16][g * 8];
      bl[nt] = *(const short8v*)&BsL[no + nt * 16 + r16][g * 8];
    }
    #pragma unroll
    for (int mt = 0; mt < 4; ++mt)
      #pragma unroll
      for (int nt = 0; nt < 4; ++nt) {
        acc[mt][nt] = __builtin_amdgcn_mfma_f32_16x16x32_bf16(ah[mt], bh[nt], acc[mt][nt], 0, 0, 0);
        if (nprod == 3) {
          acc[mt][nt] = __builtin_amdgcn_mfma_f32_16x16x32_bf16(ah[mt], bl[nt], acc[mt][nt], 0, 0, 0);
          acc[mt][nt] = __builtin_amdgcn_mfma_f32_16x16x32_bf16(al[mt], bh[nt], acc[mt][nt], 0, 0, 0);
        }
      }
    __syncthreads();
  }
  #pragma unroll
  for (int mt = 0; mt < 4; ++mt)
    #pragma unroll
    for (int nt = 0; nt < 4; ++nt) {
      float tv[4];
      int gr0 = bm + mo + mt * 16 + g * 4;
      int gc = bn + no + nt * 16 + r16;
      #pragma unroll
      for (int j = 0; j < 4; ++j) {
        int gr = gr0 + j;
        float v;
        if (omode == 5) v = ((gr == gc) ? cdiag : 0.f) - acc[mt][nt][j];
        else            v = alpha * acc[mt][nt][j];
        C[zo + (size_t)gr * 256 + gc] = v;
        tv[j] = v;
      }
      if (Ct) *(float4*)&Ct[zo + (size_t)gc * 256 + gr0] = *(float4*)&tv[0];
    }
}

// fused y0 + zinit: Y = A2*scale, Z = A2^T*scale  (scale = 1/colmax; rowsums == 1)
__global__ void k_yz0(const float* __restrict__ A2, float* __restrict__ Y,
                      float* __restrict__ Z, const unsigned int* __restrict__ sc) {
  float scale = 1.f / __uint_as_float(sc[0]);
  size_t total = (size_t)NBH * 65536;
  for (size_t idx = (size_t)blockIdx.x * blockDim.x + threadIdx.x; idx < total;
       idx += (size_t)gridDim.x * blockDim.x) {
    size_t bh = idx >> 16; int r = (int)((idx >> 8) & 255); int cc = (int)(idx & 255);
    Y[idx] = A2[idx] * scale;
    Z[idx] = A2[(bh << 16) + (size_t)cc * 256 + r] * scale;
  }
}

// --- 64x64-tile fp32 GEMM (small/batched shapes) ---
// omode 0: C = alpha*(A@B)+bias ; 5: cdiag*I-(A@B) ; 7: QL|KL split (alpha per half)
__global__ __launch_bounds__(256) void k_gemm(const float* __restrict__ A,
    const float* __restrict__ B,
    const float* __restrict__ bias, float* __restrict__ C,
    int M, int N, int K, int lda, int ldb, int ldc,
    long long sA, long long sB, long long sC, float alpha, int omode, float cdiag)
{
  __shared__ float As[16][65];
  __shared__ float Bs[16][65];
  int z = blockIdx.z;
  A += (size_t)z * (size_t)sA;
  B += (size_t)z * (size_t)sB;
  int bm = blockIdx.y * 64, bn = blockIdx.x * 64;
  int tid = threadIdx.x;
  int tr = tid >> 4, tc = tid & 15;
  int ar = tid >> 2, aq = tid & 3;
  int br = tid >> 4, bq = tid & 15;
  float acc[4][4] = {};
  for (int k0 = 0; k0 < K; k0 += 16) {
    {
      int gr = bm + ar;
      float4 v = make_float4(0.f, 0.f, 0.f, 0.f);
      if (gr < M) v = *(const float4*)&A[(size_t)gr * lda + k0 + aq * 4];
      As[aq * 4 + 0][ar] = v.x; As[aq * 4 + 1][ar] = v.y;
      As[aq * 4 + 2][ar] = v.z; As[aq * 4 + 3][ar] = v.w;
    }
    {
      float4 v = *(const float4*)&B[(size_t)(k0 + br) * ldb + bn + bq * 4];
      Bs[br][bq * 4 + 0] = v.x; Bs[br][bq * 4 + 1] = v.y;
      Bs[br][bq * 4 + 2] = v.z; Bs[br][bq * 4 + 3] = v.w;
    }
    __syncthreads();
    #pragma unroll
    for (int kk = 0; kk < 16; ++kk) {
      float a[4], bv[4];
      #pragma unroll
      for (int i = 0; i < 4; ++i) a[i] = As[kk][tr * 4 + i];
      #pragma unroll
      for (int j = 0; j < 4; ++j) bv[j] = Bs[kk][tc * 4 + j];
      #pragma unroll
      for (int i = 0; i < 4; ++i)
        #pragma unroll
        for (int j = 0; j < 4; ++j) acc[i][j] += a[i] * bv[j];
    }
    __syncthreads();
  }
  #pragma unroll
  for (int i = 0; i < 4; ++i) {
    int gr = bm + tr * 4 + i;
    if (gr >= M) continue;
    #pragma unroll
    for (int j = 0; j < 4; ++j) {
      int gc = bn + tc * 4 + j;
      if (omode == 7) {
        float v = ((gc < 512) ? 0.125f : 1.f) * acc[i][j];
        if (gc < 512) C[(size_t)gr * 512 + gc] = v;
        else          C[524288 + (size_t)gr * 512 + (gc - 512)] = v;
      } else if (omode == 5) {
        C[(size_t)z * (size_t)sC + (size_t)gr * ldc + gc] =
            ((gr == gc) ? cdiag : 0.f) - acc[i][j];
      } else {
        C[(size_t)z * (size_t)sC + (size_t)gr * ldc + gc] =
            alpha * acc[i][j] + (bias ? bias[gc] : 0.f);
      }
    }
  }
}

// gate scores + top-k softmax weights
__global__ void k_gate(const float* __restrict__ X, const float* __restrict__ gw,
                       const float* __restrict__ gb, float* __restrict__ WT, int E, int k) {
  int tok = blockIdx.x; int lane = threadIdx.x;
  const float* x = X + (size_t)tok * DMODEL;
  float s[4] = {0.f, 0.f, 0.f, 0.f};
  for (int d = lane; d < DMODEL; d += 64) {
    float xv = x[d];
    for (int e = 0; e < E; ++e) s[e] += xv * gw[(size_t)d * E + e];
  }
  #pragma unroll
  for (int off = 32; off; off >>= 1) {
    #pragma unroll
    for (int e = 0; e < 4; ++e) s[e] += __shfl_down(s[e], off);
  }
  if (lane == 0) {
    for (int e = 0; e < E; ++e) s[e] += gb[e];
    float w[4] = {0.f, 0.f, 0.f, 0.f};
    int i1 = 0;
    for (int e = 1; e < E; ++e) if (s[e] > s[i1]) i1 = e;
    if (k == 1) {
      w[i1] = 1.f;
    } else {
      int i2 = -1;
      for (int e = 0; e < E; ++e) { if (e == i1) continue; if (i2 < 0 || s[e] > s[i2]) i2 = e; }
      float e2 = expf(s[i2] - s[i1]);
      float zz = 1.f + e2;
      w[i1] = 1.f / zz; w[i2] = e2 / zz;
    }
    #pragma unroll
    for (int e = 0; e < 4; ++e) WT[(size_t)tok * 4 + e] = w[e];
  }
}

__device__ __forceinline__ void wave_ln_stats(const float* x, int lane, float& mu, float& rstd) {
  float s = 0.f, q = 0.f;
  #pragma unroll
  for (int j = 0; j < 8; ++j) { float v = x[lane + 64 * j]; s += v; q += v * v; }
  #pragma unroll
  for (int off = 32; off; off >>= 1) { s += __shfl_xor(s, off); q += __shfl_xor(q, off); }
  mu = s * (1.f / 512.f);
  float var = q * (1.f / 512.f) - mu * mu;
  rstd = rsqrtf(var + 1e-5f);
}

// gathered LN+ReLU: block i handles token lists[i] (skip if i >= cnt)
__global__ void k_ln_relu_g(float* __restrict__ T, const float* __restrict__ g,
                            const float* __restrict__ b,
                            const int* __restrict__ lists, const int* __restrict__ cnt) {
  int i = blockIdx.x;
  if (i >= *cnt) return;
  int row = lists[i];
  int lane = threadIdx.x;
  float* x = T + (size_t)row * 512;
  float mu, rstd; wave_ln_stats(x, lane, mu, rstd);
  #pragma unroll
  for (int j = 0; j < 8; ++j) {
    int d = lane + 64 * j;
    float v = (x[d] - mu) * rstd * g[d] + b[d];
    x[d] = fmaxf(v, 0.f);
  }
}

__global__ void k_ln_waccum(const float* __restrict__ T, float* __restrict__ H,
                            const float* __restrict__ g, const float* __restrict__ b,
                            const float* __restrict__ WT, int e) {
  int row = blockIdx.x;
  float w = WT[(size_t)row * 4 + e];
  if (w == 0.f) return;
  int lane = threadIdx.x;
  const float* x = T + (size_t)row * 512;
  float mu, rstd; wave_ln_stats(x, lane, mu, rstd);
  float* h = H + (size_t)row * 512;
  #pragma unroll
  for (int j = 0; j < 8; ++j) {
    int d = lane + 64 * j;
    h[d] += w * ((x[d] - mu) * rstd * g[d] + b[d]);
  }
}

// fused LN-pad + landmark group mean: one block per (b, jm); 4 waves x 6 rows.
__global__ __launch_bounds__(256) void k_ln_pad_mean(const float* __restrict__ H,
    float* __restrict__ XLn, float* __restrict__ Xm,
    const float* __restrict__ g, const float* __restrict__ b) {
  int z = blockIdx.x;            // b*256 + jm
  int bb = z >> 8, jm = z & 255;
  int wave = threadIdx.x >> 6, lane = threadIdx.x & 63;
  __shared__ float part[4][512];
  float racc[8] = {};
  for (int t6 = 0; t6 < 6; ++t6) {
    int t = wave * 6 + t6;
    int i = jm * LGRP + t;
    float* y = XLn + ((size_t)bb * NPD + i) * 512;
    if (i < PAD_FRONT) {
      #pragma unroll
      for (int j = 0; j < 8; ++j) y[lane + 64 * j] = 0.f;
      continue;
    }
    const float* x = H + ((size_t)bb * NTOK + (i - PAD_FRONT)) * 512;
    float vals[8];
    #pragma unroll
    for (int j = 0; j < 8; ++j) vals[j] = x[lane + 64 * j];
    float s = 0.f, q = 0.f;
    #pragma unroll
    for (int j = 0; j < 8; ++j) { s += vals[j]; q += vals[j] * vals[j]; }
    #pragma unroll
    for (int off = 32; off; off >>= 1) { s += __shfl_xor(s, off); q += __shfl_xor(q, off); }
    float mu = s * (1.f / 512.f);
    float rstd = rsqrtf(q * (1.f / 512.f) - mu * mu + 1e-5f);
    #pragma unroll
    for (int j = 0; j < 8; ++j) {
      int d = lane + 64 * j;
      float v = (vals[j] - mu) * rstd * g[d] + b[d];
      y[d] = v;
      racc[j] += v;
    }
  }
  #pragma unroll
  for (int j = 0; j < 8; ++j) part[wave][lane + 64 * j] = racc[j];
  __syncthreads();
  for (int c = threadIdx.x; c < 512; c += 256) {
    float s = part[0][c] + part[1][c] + part[2][c] + part[3][c];
    Xm[(size_t)z * 512 + c] = s * (1.f / LGRP);
  }
}

// max column-sum of A2 (row-sums are exactly 1: softmax) -> sc[0]
__global__ __launch_bounds__(256) void k_colmax(const float* __restrict__ A2,
                                                unsigned int* __restrict__ sc) {
  int bh = blockIdx.x; int t = threadIdx.x;
  const float* A = A2 + (size_t)bh * 65536;
  float colsum = 0.f;
  for (int jj = 0; jj < 256; ++jj) colsum += fabsf(A[(size_t)jj * 256 + t]);
  __shared__ float sh[256];
  sh[t] = colsum; __syncthreads();
  for (int s = 128; s; s >>= 1) { if (t < s) sh[t] = fmaxf(sh[t], sh[t + s]); __syncthreads(); }
  if (t == 0) atomicMax(&sc[0], __float_as_uint(sh[0]));
}

__global__ __launch_bounds__(256) void k_attn2(const float* __restrict__ QL,
                                               const float* __restrict__ KL,
                                               float* __restrict__ A2) {
  int z = blockIdx.x; int bh = z >> 8, j = z & 255;
  int b = bh >> 3, h = bh & 7;
  int t = threadIdx.x;
  __shared__ float q[64]; __shared__ float red[256];
  __shared__ float mshare, sshare;
  if (t < 64) q[t] = QL[((size_t)b * 256 + j) * 512 + h * 64 + t];
  __syncthreads();
  const float* kl = KL + ((size_t)b * 256 + t) * 512 + h * 64;
  float s = 0.f;
  #pragma unroll
  for (int d = 0; d < 64; ++d) s += q[d] * kl[d];
  red[t] = s; __syncthreads();
  for (int st = 128; st; st >>= 1) { if (t < st) red[t] = fmaxf(red[t], red[t + st]); __syncthreads(); }
  if (t == 0) mshare = red[0];
  __syncthreads();
  float e = expf(s - mshare);
  red[t] = e; __syncthreads();
  for (int st = 128; st; st >>= 1) { if (t < st) red[t] += red[t + st]; __syncthreads(); }
  if (t == 0) sshare = red[0];
  __syncthreads();
  A2[((size_t)bh * 256 + j) * 256 + t] = e / sshare;
}

// KL [b][256][512] fp32 -> KLH/KLL [bh][256][64]. grid 2048 x 256
__global__ void k_cvt_kl(const float* __restrict__ KL, unsigned short* __restrict__ KH,
                         unsigned short* __restrict__ KLo) {
  int idx = blockIdx.x * 256 + threadIdx.x;
  int bh = idx >> 14, j = (idx >> 6) & 255, d = idx & 63;
  int b = bh >> 3, h = bh & 7;
  float v = KL[((size_t)b * 256 + j) * 512 + h * 64 + d];
  unsigned short hi = f2bf(v);
  KH[idx] = hi; KLo[idx] = f2bf(v - bf2f(hi));
}

// W2b [bh][256][64] fp32 -> W2t hi/lo [bh][64][256]. grid 2048 x 256
__global__ void k_cvt_w2t(const float* __restrict__ W2b, unsigned short* __restrict__ WH,
                          unsigned short* __restrict__ WL) {
  int idx = blockIdx.x * 256 + threadIdx.x;
  int bh = idx >> 14, d = (idx >> 8) & 63, j = idx & 255;
  float v = W2b[((size_t)bh * 256 + j) * 64 + d];
  unsigned short hi = f2bf(v);
  WH[idx] = hi; WL[idx] = f2bf(v - bf2f(hi));
}

// ---- MFMA flash attention, pre-split K/V; P hi-only PV ----
__global__ __launch_bounds__(256) void k_flash_pre(
    const float* __restrict__ Qp, long long Qsb, long long Qsh, int Qsr,
    const unsigned short* __restrict__ KHg, const unsigned short* __restrict__ KLg,
    long long Ksbh,
    const unsigned short* __restrict__ VtHg, const unsigned short* __restrict__ VtLg,
    long long Vsbh, int Vrow,
    float* __restrict__ Op, long long Osb, long long Osh, int Osr,
    float* __restrict__ Opart, float* __restrict__ ML,
    int tiles_per_chunk, int mode)
{
  int jt = blockIdx.x, bh = blockIdx.y, ch = blockIdx.z;
  int b = bh >> 3, h = bh & 7;
  const float* Qb = Qp + (size_t)b * Qsb + (size_t)h * Qsh;
  const unsigned short* KbH = KHg + (size_t)bh * Ksbh;
  const unsigned short* KbL = KLg + (size_t)bh * Ksbh;
  const unsigned short* VbH = VtHg + (size_t)bh * Vsbh;
  const unsigned short* VbL = VtLg + (size_t)bh * Vsbh;
  int tid = threadIdx.x;
  int wave = tid >> 6, lane = tid & 63;
  int r16 = lane & 15, g = lane >> 4;
  int q0 = jt * 64 + wave * 16;

  __shared__ unsigned short KsH[64][72], KsL[64][72];   // K; KsH reused as P after QK
  __shared__ unsigned short VtH[64][72], VtL[64][72];   // V transposed [d][key]

  short8v qh[2], ql[2];
  #pragma unroll
  for (int kk = 0; kk < 2; ++kk) {
    const float* qr = Qb + (size_t)(q0 + r16) * Qsr + kk * 32 + g * 8;
    float4 v0 = *(const float4*)qr;
    float4 v1 = *(const float4*)(qr + 4);
    float vs[8] = {v0.x, v0.y, v0.z, v0.w, v1.x, v1.y, v1.z, v1.w};
    unsigned short hh[8], llo[8];
    #pragma unroll
    for (int e = 0; e < 8; ++e) {
      hh[e] = f2bf(vs[e]); llo[e] = f2bf(vs[e] - bf2f(hh[e]));
    }
    qh[kk] = *(short8v*)&hh[0];
    ql[kk] = *(short8v*)&llo[0];
  }

  f32x4 O4[4] = {};
  float m[4], lsum[4];
  #pragma unroll
  for (int j = 0; j < 4; ++j) { m[j] = -1e30f; lsum[j] = 0.f; }

  int t0 = ch * tiles_per_chunk;
  for (int tt = t0; tt < t0 + tiles_per_chunk; ++tt) {
    int key0 = tt * 64;
    __syncthreads();
    {
      const unsigned short* ksrcH = KbH + (size_t)key0 * 64;
      const unsigned short* ksrcL = KbL + (size_t)key0 * 64;
      #pragma unroll
      for (int u = 0; u < 2; ++u) {
        int idx = tid + 256 * u;
        int r = idx >> 3, c8 = (idx & 7) * 8;
        *(short8v*)&KsH[r][c8] = *(const short8v*)&ksrcH[idx * 8];
        *(short8v*)&KsL[r][c8] = *(const short8v*)&ksrcL[idx * 8];
      }
      const unsigned short* vsrcH = VbH + key0;
      const unsigned short* vsrcL = VbL + key0;
      #pragma unroll
      for (int u = 0; u < 2; ++u) {
        int idx = tid + 256 * u;
        int d = idx >> 3, c8 = (idx & 7) * 8;
        *(short8v*)&VtH[d][c8] = *(const short8v*)&vsrcH[(size_t)d * Vrow + c8];
        *(short8v*)&VtL[d][c8] = *(const short8v*)&vsrcL[(size_t)d * Vrow + c8];
      }
    }
    __syncthreads();
    f32x4 S[4] = {};
    #pragma unroll
    for (int kk = 0; kk < 2; ++kk)
      #pragma unroll
      for (int nt = 0; nt < 4; ++nt) {
        short8v kh = *(const short8v*)&KsH[nt * 16 + r16][kk * 32 + g * 8];
        short8v kl = *(const short8v*)&KsL[nt * 16 + r16][kk * 32 + g * 8];
        S[nt] = __builtin_amdgcn_mfma_f32_16x16x32_bf16(qh[kk], kh, S[nt], 0, 0, 0);
        S[nt] = __builtin_amdgcn_mfma_f32_16x16x32_bf16(qh[kk], kl, S[nt], 0, 0, 0);
        S[nt] = __builtin_amdgcn_mfma_f32_16x16x32_bf16(ql[kk], kh, S[nt], 0, 0, 0);
      }
    float tmax[4];
    #pragma unroll
    for (int j = 0; j < 4; ++j)
      tmax[j] = fmaxf(fmaxf(S[0][j], S[1][j]), fmaxf(S[2][j], S[3][j]));
    #pragma unroll
    for (int off = 8; off; off >>= 1)
      #pragma unroll
      for (int j = 0; j < 4; ++j) tmax[j] = fmaxf(tmax[j], __shfl_xor(tmax[j], off));
    float corr[4];
    #pragma unroll
    for (int j = 0; j < 4; ++j) {
      float mn = fmaxf(m[j], tmax[j]);
      corr[j] = expf(m[j] - mn);
      m[j] = mn;
    }
    __syncthreads();
    float tl[4] = {0.f, 0.f, 0.f, 0.f};
    #pragma unroll
    for (int nt = 0; nt < 4; ++nt)
      #pragma unroll
      for (int j = 0; j < 4; ++j) {
        float p = expf(S[nt][j] - m[j]);
        tl[j] += p;
        KsH[wave * 16 + g * 4 + j][nt * 16 + r16] = f2bf(p);   // P hi only
      }
    #pragma unroll
    for (int off = 8; off; off >>= 1)
      #pragma unroll
      for (int j = 0; j < 4; ++j) tl[j] += __shfl_xor(tl[j], off);
    #pragma unroll
    for (int j = 0; j < 4; ++j) lsum[j] = lsum[j] * corr[j] + tl[j];
    #pragma unroll
    for (int nt = 0; nt < 4; ++nt)
      #pragma unroll
      for (int j = 0; j < 4; ++j) O4[nt][j] *= corr[j];
    #pragma unroll
    for (int kk = 0; kk < 2; ++kk) {
      short8v ph = *(const short8v*)&KsH[wave * 16 + r16][kk * 32 + g * 8];
      #pragma unroll
      for (int nt = 0; nt < 4; ++nt) {
        short8v vh = *(const short8v*)&VtH[nt * 16 + r16][kk * 32 + g * 8];
        short8v vl = *(const short8v*)&VtL[nt * 16 + r16][kk * 32 + g * 8];
        O4[nt] = __builtin_amdgcn_mfma_f32_16x16x32_bf16(ph, vh, O4[nt], 0, 0, 0);
        O4[nt] = __builtin_amdgcn_mfma_f32_16x16x32_bf16(ph, vl, O4[nt], 0, 0, 0);
      }
    }
  }
  if (mode == 0) {
    float* Ob = Op + (size_t)b * Osb + (size_t)h * Osh;
    float inv[4];
    #pragma unroll
    for (int j = 0; j < 4; ++j) inv[j] = 1.f / lsum[j];
    #pragma unroll
    for (int nt = 0; nt < 4; ++nt)
      #pragma unroll
      for (int j = 0; j < 4; ++j)
        Ob[(size_t)(q0 + g * 4 + j) * Osr + nt * 16 + r16] = O4[nt][j] * inv[j];
  } else {
    #pragma unroll
    for (int j = 0; j < 4; ++j) {
      size_t rowbase = ((size_t)ch * NBH + bh) * 256 + q0 + g * 4 + j;
      #pragma unroll
      for (int nt = 0; nt < 4; ++nt)
        Opart[rowbase * 64 + nt * 16 + r16] = O4[nt][j];
      if (r16 == 0) { ML[rowbase * 2] = m[j]; ML[rowbase * 2 + 1] = lsum[j]; }
    }
  }
}

// combine NCH chunks -> A3V[bh,256,64]. grid (16, NBH), 256 thr.
__global__ __launch_bounds__(256) void k_flash_comb(const float* __restrict__ Opart,
                                                    const float* __restrict__ ML,
                                                    float* __restrict__ A3V) {
  int jt = blockIdx.x, bh = blockIdx.y;
  int t = threadIdx.x;
  int jr = t >> 4, q16 = t & 15;
  int row = jt * 16 + jr;
  float mv[NCH], lv[NCH];
  float M = -1e30f;
  #pragma unroll
  for (int ch = 0; ch < NCH; ++ch) {
    size_t base = (((size_t)ch * NBH + bh) * 256 + row);
    mv[ch] = ML[base * 2]; lv[ch] = ML[base * 2 + 1];
    M = fmaxf(M, mv[ch]);
  }
  float L = 0.f;
  float4 O = make_float4(0.f, 0.f, 0.f, 0.f);
  #pragma unroll
  for (int ch = 0; ch < NCH; ++ch) {
    float c = expf(mv[ch] - M);
    L += c * lv[ch];
    size_t base = (((size_t)ch * NBH + bh) * 256 + row);
    float4 o = *(const float4*)&Opart[base * 64 + q16 * 4];
    O.x += c * o.x; O.y += c * o.y; O.z += c * o.z; O.w += c * o.w;
  }
  float inv = 1.f / L;
  *(float4*)&A3V[((size_t)bh * 256 + row) * 64 + q16 * 4] =
      make_float4(O.x * inv, O.y * inv, O.z * inv, O.w * inv);
}

// conv over i from Vt hi/lo; grid (NPD/128, NBH), 256 thr.
__global__ __launch_bounds__(256) void k_conv_add(const unsigned short* __restrict__ VtHg,
    const unsigned short* __restrict__ VtLg, const float* __restrict__ cw,
    float* __restrict__ out) {
  int it = blockIdx.x, bh = blockIdx.y;
  int b = bh >> 3, h = bh & 7;
  int i0 = it * 128;
  int t = threadIdx.x;
  __shared__ float Vs[64][161];
  const unsigned short* vh = VtHg + (size_t)bh * 64 * NPD;
  const unsigned short* vl = VtLg + (size_t)bh * 64 * NPD;
  for (int u = 0; u < 40; ++u) {
    int idx = t + 256 * u;
    int d = idx / 160, ii = idx - d * 160;
    int gi = i0 - 16 + ii;
    float v = 0.f;
    if (gi >= 0 && gi < NPD) {
      size_t a = (size_t)d * NPD + gi;
      v = bf2f(vh[a]) + bf2f(vl[a]);
    }
    Vs[d][ii] = v;
  }
  __syncthreads();
  float w[CONVK];
  #pragma unroll
  for (int p = 0; p < CONVK; ++p) w[p] = cw[h * CONVK + p];
  int rgrp = t >> 6, d = t & 63;
  for (int r = rgrp * 32; r < rgrp * 32 + 32; ++r) {
    float acc = 0.f;
    #pragma unroll
    for (int p = 0; p < CONVK; ++p) acc += w[p] * Vs[d][r + p];
    out[((size_t)b * NPD + i0 + r) * 512 + h * 64 + d] += acc;
  }
}

__global__ void k_out_write(const float* __restrict__ H, float* __restrict__ out) {
  size_t n0 = (size_t)BATCH * 512;
  size_t total = n0 + (size_t)BATCH * (NTOK - 1) * 512;
  for (size_t idx = (size_t)blockIdx.x * blockDim.x + threadIdx.x; idx < total;
       idx += (size_t)gridDim.x * blockDim.x) {
    float v;
    if (idx < n0) {
      int b = (int)(idx >> 9); int d = (int)(idx & 511);
      v = H[((size_t)b * NTOK) * 512 + d];
    } else {
      size_t r = idx - n0;
      size_t bj = r >> 9; int d = (int)(r & 511);
      int b = (int)(bj / (NTOK - 1)); int j = (int)(bj % (NTOK - 1));
      v = H[((size_t)b * NTOK + 1 + j) * 512 + d];
    }
    out[idx] = v;
  }
}

// ============================ host ============================

extern "C" void kernel_launch(void* const* d_in, const int* in_sizes, int n_in,
                              void* d_out, int out_size, void* d_ws, size_t ws_size,
                              hipStream_t stream) {
  (void)in_sizes; (void)n_in;

  const float* feat = (const float*)d_in[0];
  const float* cls  = (const float*)d_in[1];
  const float* m1_gw = (const float*)d_in[2];  const float* m1_gb = (const float*)d_in[3];
  const float* m1_f1w = (const float*)d_in[4]; const float* m1_f1b = (const float*)d_in[5];
  const float* m1_l1g = (const float*)d_in[6]; const float* m1_l1b = (const float*)d_in[7];
  const float* m1_f2w = (const float*)d_in[8]; const float* m1_f2b = (const float*)d_in[9];
  const float* m1_l2g = (const float*)d_in[10]; const float* m1_l2b = (const float*)d_in[11];
  const float* m2_gw = (const float*)d_in[12]; const float* m2_gb = (const float*)d_in[13];
  const float* m2_f1w = (const float*)d_in[14]; const float* m2_f1b = (const float*)d_in[15];
  const float* m2_l1g = (const float*)d_in[16]; const float* m2_l1b = (const float*)d_in[17];
  const float* m2_f2w = (const float*)d_in[18]; const float* m2_f2b = (const float*)d_in[19];
  const float* m2_l2g = (const float*)d_in[20]; const float* m2_l2b = (const float*)d_in[21];
  const float* l1_ng = (const float*)d_in[22]; const float* l1_nb = (const float*)d_in[23];
  const float* l1_qkvw = (const float*)d_in[24]; const float* l1_outw = (const float*)d_in[25];
  const float* l1_outb = (const float*)d_in[26]; const float* l1_convw = (const float*)d_in[27];
  const float* l2_ng = (const float*)d_in[28]; const float* l2_nb = (const float*)d_in[29];
  const float* l2_qkvw = (const float*)d_in[30]; const float* l2_outw = (const float*)d_in[31];
  const float* l2_outb = (const float*)d_in[32]; const float* l2_convw = (const float*)d_in[33];

  // ---- workspace layout (units: fp32 elements) ----
  constexpr size_t SZ_H    = (size_t)BN_TOK * 512;
  constexpr size_t SZ_ROW  = (size_t)RPAD * 512;
  float* W = (float*)d_ws;
  float* H  = W;
  float* WT = W + SZ_H;
  unsigned int* SC = (unsigned int*)(W + SZ_H + 97360);
  float* pool = W + SZ_H + 97360 + 16;

  float* R2 = pool;                    // XLn -> AttnO ; MoE T1
  float* R3 = pool + SZ_ROW;           // K hi/lo -> Qb ; MoE T2
  float* R4 = pool + 2 * SZ_ROW;       // Vt hi/lo ; MoE Xsnap
  float* SMALL = pool + 3 * SZ_ROW;
  float* Xm  = SMALL;                  // 524288; later ML for flash3
  float* QL  = SMALL + 524288;
  float* KL  = SMALL + 1048576;        // contiguous after QL (omode-7 split write)
  float* A2  = SMALL + 1572864;        // 2.1M; MoE: per-expert Bt; post-pinv: KLH/...
  float* Zb  = SMALL + 3670016;        // MoE: LISTS; pinv Y; post-pinv: Opart
  float* XZp = SMALL + 5767168;        // pinv F1
  float* Wa  = SMALL + 7864320;        // pinv F2; post-pinv: qkv/out weight Bt
  float* Wb  = SMALL + 9961472;        // pinv Z (z_final)
  float* A3V = SMALL + 12058624;
  float* W2b = SMALL + 12582912;
  size_t total_f = (SZ_H + 97360 + 16) + 3 * SZ_ROW + 13107200;
  if (total_f * 4 > ws_size) {
    k_diag_fill<<<2048, 256, 0, stream>>>((float*)d_out, (size_t)out_size,
                                          (float)(ws_size >> 20));
    return;
  }

  k_build_h<<<2048, 256, 0, stream>>>(feat, cls, H);

  auto run_moe = [&](const float* gw, const float* gb, const float* f1w, const float* f1b,
                     const float* l1g, const float* l1b, const float* f2w, const float* f2b,
                     const float* l2g, const float* l2b, int E, int k) {
    float* T1 = R2; float* T2 = R3; float* Xsnap = R4;
    unsigned short* BtF1H = (unsigned short*)A2;
    unsigned short* BtF1L = BtF1H + (size_t)E * 262144;
    unsigned short* BtF2H = (unsigned short*)(A2 + 1048576);
    unsigned short* BtF2L = BtF2H + (size_t)E * 262144;
    int* LISTS = (int*)Zb;
    int* CNT = (int*)(SC + 4);
    hipMemcpyAsync(Xsnap, H, SZ_H * 4, hipMemcpyDeviceToDevice, stream);
    hipMemsetAsync(CNT, 0, 4 * sizeof(int), stream);
    k_gate<<<BN_TOK, 64, 0, stream>>>(H, gw, gb, WT, E, k);
    k_lists<<<(BN_TOK + 63) / 64, 64, 0, stream>>>(WT, CNT, LISTS, E);
    k_wconv<<<dim3(8, 8, E), 256, 0, stream>>>(f1w, 512, 262144LL, BtF1H, BtF1L, 262144LL);
    k_wconv<<<dim3(8, 8, E), 256, 0, stream>>>(f2w, 512, 262144LL, BtF2H, BtF2L, 262144LL);
    dim3 g(4, (BN_TOK + 127) / 128, 1);
    for (int e = 0; e < E; ++e) {
      const int* lst = LISTS + (size_t)e * LISTCAP;
      const int* cnt = CNT + e;
      k_gemm_mfma<<<g, 256, 0, stream>>>(Xsnap, BtF1H + (size_t)e * 262144,
          BtF1L + (size_t)e * 262144, f1b + e * 512, T1,
          BN_TOK, 512, 512, 1.f, 0, nullptr, lst, cnt, nullptr, nullptr);
      k_ln_relu_g<<<BN_TOK, 64, 0, stream>>>(T1, l1g + e * 512, l1b + e * 512, lst, cnt);
      k_gemm_mfma<<<g, 256, 0, stream>>>(T1, BtF2H + (size_t)e * 262144,
          BtF2L + (size_t)e * 262144, f2b + e * 512, T2,
          BN_TOK, 512, 512, 1.f, 0, nullptr, lst, cnt, nullptr, nullptr);
      k_ln_waccum<<<BN_TOK, 64, 0, stream>>>(T2, H, l2g + e * 512, l2b + e * 512, WT, e);
    }
  };

  auto run_attn = [&](const float* ng, const float* nb, const float* qkvw, const float* outw,
                      const float* outb, const float* convw) {
    float* XLn = R2; float* AttnO = R2;
    float* Qb = R3;
    unsigned short* KH  = (unsigned short*)R3;
    unsigned short* KLo = KH + 12582912;
    unsigned short* VtH = (unsigned short*)R4;
    unsigned short* VtL = VtH + 12582912;
    // fused LN-pad + landmark mean
    k_ln_pad_mean<<<BATCH * 256, 256, 0, stream>>>(H, XLn, Xm, ng, nb);
    // merged QL|KL projection (omode 7)
    k_gemm<<<dim3(16, 16, 1), 256, 0, stream>>>(Xm, qkvw, nullptr, QL,
        1024, 1024, 512, 512, 1536, 512, 0, 0, 0, 1.f, 7, 0.f);
    k_attn2<<<NBH * 256, 256, 0, stream>>>(QL, KL, A2);
    hipMemsetAsync(SC, 0, 8, stream);
    k_colmax<<<NBH, 256, 0, stream>>>(A2, SC);
    // ---- pinv Newton-Schulz: 4 fused dispatches/iter (transpose in epilogue) ----
    k_yz0<<<2048, 256, 0, stream>>>(A2, Zb, Wb, SC);   // Y = z^T, Z = z
    float* Y = Zb; float* Z = Wb; float* F1 = XZp; float* F2 = Wa;
    dim3 gq(2, 2, NBH);
    for (int it = 0; it < 6; ++it) {
      int np = (it < 4) ? 1 : 3;
      k_gemm_mfma2<<<gq, 256, 0, stream>>>(A2, Y, F1, 1.f, 0, 0.f, 0, np, F2);   // F1=XZ, F2=XZT
      k_gemm_mfma2<<<gq, 256, 0, stream>>>(F2, F1, Y, 1.f, 5, 15.f, 1, np, nullptr); // Y=QT
      k_gemm_mfma2<<<gq, 256, 0, stream>>>(Y, F1, F2, 1.f, 5, 13.f, 0, np, nullptr); // F2=PT
      k_gemm_mfma2<<<gq, 256, 0, stream>>>(Z, F2, F1, 0.25f, 0, 0.f, 0, np, Y);  // F1=z_new, Y=z_new^T
      float* tz = Z; Z = F1; F1 = tz;
    }
    // z_final in Z. A2 region reusable now.
    unsigned short* KLH = (unsigned short*)A2;
    unsigned short* KLL = KLH + 524288;
    unsigned short* W2tH = KLH + 1048576;
    unsigned short* W2tL = KLH + 1572864;
    k_cvt_kl<<<2048, 256, 0, stream>>>(KL, KLH, KLL);
    unsigned short* BtQH = (unsigned short*)Wa;
    unsigned short* BtQL = BtQH + 786432;
    k_wconv<<<dim3(24, 8, 1), 256, 0, stream>>>(qkvw, 1536, 0LL, BtQH, BtQL, 0LL);
    dim3 gr(4, (RPAD + 127) / 128, 1);
    // fused K+V projection: K -> packed rows (R3), V -> transposed (R4). omode 8.
    k_gemm_mfma<<<dim3(8, (RPAD + 127) / 128, 1), 256, 0, stream>>>(
        XLn, BtQH + 512 * 512, BtQL + 512 * 512, nullptr,
        (float*)KH, RPAD, 512, 512, 1.f, 8, KLo, nullptr, nullptr, VtH, VtL);
    // attn3: split-kv flash; Opart in Zb..XZp (4.19M), ML in Xm
    k_flash_pre<<<dim3(4, NBH, NCH), 256, 0, stream>>>(
        QL, 131072LL, 64LL, 512,
        KH, KLo, (long long)NPD * 64,
        VtH, VtL, (long long)64 * NPD, NPD,
        nullptr, 0, 0, 0, Zb, Xm, NPD / (64 * NCH), 1);
    k_flash_comb<<<dim3(16, NBH), 256, 0, stream>>>(Zb, Xm, A3V);
    // W2b[bh] = z_final @ A3V
    k_gemm<<<dim3(1, 4, NBH), 256, 0, stream>>>(Z, A3V, nullptr, W2b,
        256, 64, 256, 256, 64, 64, 65536, 16384, 16384, 1.f, 0, 0.f);
    k_cvt_w2t<<<2048, 256, 0, stream>>>(W2b, W2tH, W2tL);
    // Q projection (scaled) -> fp32 R3 (K dead after flash3)
    k_gemm_mfma<<<gr, 256, 0, stream>>>(XLn, BtQH, BtQL, nullptr,
        Qb, RPAD, 512, 512, 0.125f, 0, nullptr, nullptr, nullptr, nullptr, nullptr);
    // attn1 flash -> AttnO (over XLn, dead after Q proj)
    k_flash_pre<<<dim3(NPD / 64, NBH, 1), 256, 0, stream>>>(
        Qb, (long long)NPD * 512, 64LL, 512,
        KLH, KLL, 16384LL,
        W2tH, W2tL, 16384LL, 256,
        AttnO, (long long)NPD * 512, 64LL, 512,
        nullptr, nullptr, 4, 0);
    k_conv_add<<<dim3(NPD / 128, NBH), 256, 0, stream>>>(VtH, VtL, convw, AttnO);
    // out-proj, cropped + accumulated into H (Bt in Wa, dead)
    unsigned short* BtOH = (unsigned short*)Wa;
    unsigned short* BtOL = BtOH + 262144;
    k_wconv<<<dim3(8, 8, 1), 256, 0, stream>>>(outw, 512, 0LL, BtOH, BtOL, 0LL);
    k_gemm_mfma<<<gr, 256, 0, stream>>>(AttnO, BtOH, BtOL, outb,
        H, RPAD, 512, 512, 1.f, 2, nullptr, nullptr, nullptr, nullptr, nullptr);
  };

  run_moe(m1_gw, m1_gb, m1_f1w, m1_f1b, m1_l1g, m1_l1b, m1_f2w, m1_f2b, m1_l2g, m1_l2b, 2, 1);
  run_attn(l1_ng, l1_nb, l1_qkvw, l1_outw, l1_outb, l1_convw);
  run_moe(m2_gw, m2_gb, m2_f1w, m2_f1b, m2_l1g, m2_l1b, m2_f2w, m2_f2b, m2_l2g, m2_l2b, 4, 2);
  run_attn(l2_ng, l2_nb, l2_qkvw, l2_outw, l2_outb, l2_convw);

  k_out_write<<<2048, 256, 0, stream>>>(H, (float*)d_out);
}